// Round 1
// baseline (1415.992 us; speedup 1.0000x reference)
//
#include <hip/hip_runtime.h>
#include <math.h>

#define B_    1024
#define DE    200
#define DR    200
#define NFC   32
#define LFC   9
#define LL    192          // DE - LFC + 1
#define FC1LEN 288         // NFC*LFC
#define FCLEN 6144         // NFC*LL
#define NENT  100000
#define EPSI  1e-5f

// ---- workspace layout (float offsets) ----
#define O_S0   0           // s0,t0 (2)
#define O_P0   64          // bn0 partials: 64 blocks x 2
#define O_S1   256         // s1[32], t1[32]
#define O_S2   320         // s2[200], t2[200]
#define O_P1   768         // bn1 partials: 1024 x 32 x 2 = 65536
#define O_X    66304       // x: 1024x200
#define O_K    271104      // k: 1024x288
#define O_CONV 566016      // conv: 1024x6144
#define O_Y    6857472     // y: 1024x200
#define O_AR   7062272     // relu(bn2(y)): 1024x200
#define O_PART 7267072     // y-gemm partials: 8 x 204800
// end: 8905472 floats = 35.6 MB

__device__ __forceinline__ float sigm(float x){
  return __fdividef(1.0f, 1.0f + __expf(-x));
}

// ---------- BN0: global mean/var of e1 ----------
__global__ void k_bn0_part(const float* __restrict__ e1, float* __restrict__ ws){
  __shared__ float ss[256], sq[256];
  int tid = threadIdx.x;
  float a = 0.f, b = 0.f;
  for (int i = blockIdx.x*256 + tid; i < B_*DE; i += 64*256){
    float v = e1[i]; a += v; b += v*v;
  }
  ss[tid]=a; sq[tid]=b; __syncthreads();
  for (int s=128; s>0; s>>=1){
    if (tid < s){ ss[tid]+=ss[tid+s]; sq[tid]+=sq[tid+s]; }
    __syncthreads();
  }
  if (tid==0){ ws[O_P0+2*blockIdx.x]=ss[0]; ws[O_P0+2*blockIdx.x+1]=sq[0]; }
}

__global__ void k_bn0_final(const float* __restrict__ g, const float* __restrict__ bt,
                            float* __restrict__ ws){
  int tid = threadIdx.x;  // 64 threads = 1 wave
  float a = ws[O_P0+2*tid], b = ws[O_P0+2*tid+1];
  for (int o=32; o>0; o>>=1){ a += __shfl_down(a,o); b += __shfl_down(b,o); }
  if (tid==0){
    float n = (float)(B_*DE);
    float m = a/n;
    float v = b/n - m*m;
    float s = rsqrtf(v + EPSI) * g[0];
    ws[O_S0]   = s;
    ws[O_S0+1] = bt[0] - m*s;
  }
}

__global__ void k_x(const float* __restrict__ e1, float* __restrict__ ws){
  float s = ws[O_S0], t = ws[O_S0+1];
  int i = blockIdx.x*256 + threadIdx.x;   // grid exactly covers 204800
  ws[O_X+i] = e1[i]*s + t;
}

// ---------- FC1: k = r @ fc1_w.T + fc1_b  (per-sample filters) ----------
__global__ void k_fc1(const float* __restrict__ r, const float* __restrict__ w,
                      const float* __restrict__ bias, float* __restrict__ ws){
  __shared__ float rs[DR];
  int b = blockIdx.x;
  for (int d = threadIdx.x; d < DR; d += 256) rs[d] = r[b*DR + d];
  __syncthreads();
  for (int i = threadIdx.x; i < FC1LEN; i += 256){
    const float* wr = w + (size_t)i*DR;
    float acc = bias[i];
    #pragma unroll 4
    for (int d = 0; d < DR; ++d) acc += rs[d]*wr[d];
    ws[O_K + b*FC1LEN + i] = acc;
  }
}

// ---------- conv: conv[b,f,l] = sum_j x[b,l+j]*k[b,f,j]; also bn1 partials ----------
__global__ void k_conv(float* __restrict__ ws){
  __shared__ float xs[DE];
  __shared__ float kf[FC1LEN];
  int b = blockIdx.x, tid = threadIdx.x;
  for (int d = tid; d < DE;     d += 256) xs[d] = ws[O_X + b*DE + d];
  for (int i = tid; i < FC1LEN; i += 256) kf[i] = ws[O_K + b*FC1LEN + i];
  __syncthreads();
  int f = tid >> 3, sub = tid & 7;
  float kr[LFC];
  #pragma unroll
  for (int j = 0; j < LFC; ++j) kr[j] = kf[f*LFC + j];
  float sum = 0.f, sq = 0.f;
  #pragma unroll 4
  for (int t = 0; t < 24; ++t){
    int l = sub + 8*t;
    float acc = 0.f;
    #pragma unroll
    for (int j = 0; j < LFC; ++j) acc += xs[l+j]*kr[j];
    ws[O_CONV + b*FCLEN + f*LL + l] = acc;
    sum += acc; sq += acc*acc;
  }
  // reduce over 8 lanes sharing f
  for (int o = 1; o < 8; o <<= 1){ sum += __shfl_xor(sum,o); sq += __shfl_xor(sq,o); }
  if (sub == 0){
    ws[O_P1 + (b*NFC + f)*2    ] = sum;
    ws[O_P1 + (b*NFC + f)*2 + 1] = sq;
  }
}

__global__ void k_bn1_final(const float* __restrict__ g, const float* __restrict__ bt,
                            float* __restrict__ ws){
  __shared__ float ss[256], sq[256];
  int f = blockIdx.x, tid = threadIdx.x;
  float a = 0.f, b = 0.f;
  for (int i = tid; i < B_; i += 256){
    a += ws[O_P1 + (i*NFC + f)*2];
    b += ws[O_P1 + (i*NFC + f)*2 + 1];
  }
  ss[tid]=a; sq[tid]=b; __syncthreads();
  for (int s=128; s>0; s>>=1){
    if (tid < s){ ss[tid]+=ss[tid+s]; sq[tid]+=sq[tid+s]; }
    __syncthreads();
  }
  if (tid==0){
    float n = (float)(B_*LL);
    float m = ss[0]/n, v = sq[0]/n - m*m;
    float s = rsqrtf(v + EPSI) * g[f];
    ws[O_S1 + f]       = s;
    ws[O_S1 + NFC + f] = bt[f] - m*s;
  }
}

// ---------- y-GEMM: y[b,o] = sum_i (conv[b,i]*s1[f]+t1[f]) * fc_w[o,i]  (K-split 8) ----------
#define FMA16(A0,A1,A2,A3,a,w) \
  A0.x += a.x*w.x; A0.y += a.x*w.y; A0.z += a.x*w.z; A0.w += a.x*w.w; \
  A1.x += a.y*w.x; A1.y += a.y*w.y; A1.z += a.y*w.z; A1.w += a.y*w.w; \
  A2.x += a.z*w.x; A2.y += a.z*w.y; A2.z += a.z*w.z; A2.w += a.z*w.w; \
  A3.x += a.w*w.x; A3.y += a.w*w.y; A3.z += a.w*w.z; A3.w += a.w*w.w;

__global__ __launch_bounds__(256) void k_ygemm(const float* __restrict__ fcw,
                                               float* __restrict__ ws){
  __shared__ __align__(16) float As[64][64];
  __shared__ __align__(16) float Bs[64][64];
  __shared__ float s1s[2*NFC];
  const float* conv = ws + O_CONV;
  int tid = threadIdx.x;
  if (tid < 2*NFC) s1s[tid] = ws[O_S1 + tid];
  int n0 = blockIdx.x*64;     // o tile (0,64,128,192)
  int m0 = blockIdx.y*64;     // b tile
  int seg = blockIdx.z;       // K segment (768 each)
  float4 a0 = {0,0,0,0}, a1 = {0,0,0,0}, a2 = {0,0,0,0}, a3 = {0,0,0,0};
  for (int ch = 0; ch < 12; ++ch){
    int ks = seg*768 + ch*64;
    __syncthreads();
    #pragma unroll
    for (int t = 0; t < 16; ++t){
      int idx = tid + 256*t;
      int r = idx & 63, kk = idx >> 6;
      int i = ks + kk;
      int f = i / LL;
      float v = conv[(size_t)(m0 + r)*FCLEN + i];
      As[kk][r] = v*s1s[f] + s1s[NFC + f];
    }
    #pragma unroll
    for (int t = 0; t < 16; ++t){
      int idx = tid + 256*t;
      int r = idx & 63, kk = idx >> 6;
      int o = n0 + r;
      Bs[kk][r] = (o < DE) ? fcw[(size_t)o*FCLEN + ks + kk] : 0.f;
    }
    __syncthreads();
    int rt = tid >> 4, ct = tid & 15;
    #pragma unroll 8
    for (int kk = 0; kk < 64; ++kk){
      float4 a = *(const float4*)&As[kk][rt*4];
      float4 w = *(const float4*)&Bs[kk][ct*4];
      FMA16(a0,a1,a2,a3,a,w)
    }
  }
  int rt = tid >> 4, ct = tid & 15;
  int o = n0 + ct*4;
  if (o < DE){
    float* part = ws + O_PART + (size_t)seg*(B_*DE);
    float4* p0 = (float4*)&part[(m0 + rt*4 + 0)*DE + o];
    float4* p1 = (float4*)&part[(m0 + rt*4 + 1)*DE + o];
    float4* p2 = (float4*)&part[(m0 + rt*4 + 2)*DE + o];
    float4* p3 = (float4*)&part[(m0 + rt*4 + 3)*DE + o];
    *p0 = a0; *p1 = a1; *p2 = a2; *p3 = a3;
  }
}

__global__ void k_yreduce(const float* __restrict__ fcb, float* __restrict__ ws){
  int i = blockIdx.x*256 + threadIdx.x;   // covers exactly 204800
  int o = i % DE;
  float y = fcb[o];
  #pragma unroll
  for (int s = 0; s < 8; ++s) y += ws[O_PART + s*(B_*DE) + i];
  ws[O_Y + i] = y;
}

// ---------- BN2 per-column stats over batch ----------
__global__ void k_bn2(const float* __restrict__ g, const float* __restrict__ bt,
                      float* __restrict__ ws){
  __shared__ float ss[256], sq[256];
  int o = blockIdx.x, tid = threadIdx.x;
  float a = 0.f, b = 0.f;
  for (int i = tid; i < B_; i += 256){
    float v = ws[O_Y + i*DE + o];
    a += v; b += v*v;
  }
  ss[tid]=a; sq[tid]=b; __syncthreads();
  for (int s=128; s>0; s>>=1){
    if (tid < s){ ss[tid]+=ss[tid+s]; sq[tid]+=sq[tid+s]; }
    __syncthreads();
  }
  if (tid==0){
    float n = (float)B_;
    float m = ss[0]/n, v = sq[0]/n - m*m;
    float s = rsqrtf(v + EPSI) * g[o];
    ws[O_S2 + o]      = s;
    ws[O_S2 + DE + o] = bt[o] - m*s;
  }
}

__global__ void k_arelu(float* __restrict__ ws){
  int i = blockIdx.x*256 + threadIdx.x;   // 204800
  int o = i % DE;
  float v = ws[O_Y + i]*ws[O_S2 + o] + ws[O_S2 + DE + o];
  ws[O_AR + i] = fmaxf(v, 0.f);
}

// ---------- scores GEMM: out[b,n] = sigmoid( A[b,:] . E[n,:] + bias[n] ) ----------
__global__ __launch_bounds__(256) void k_biggemm(const float* __restrict__ E,
                                                 const float* __restrict__ bias,
                                                 const float* __restrict__ ws,
                                                 float* __restrict__ out){
  __shared__ __align__(16) float As[40][64];
  __shared__ __align__(16) float Es[40][64];
  const float* A = ws + O_AR;
  int tid = threadIdx.x;
  int n0 = blockIdx.x*64;
  int m0 = blockIdx.y*64;
  float4 a0 = {0,0,0,0}, a1 = {0,0,0,0}, a2 = {0,0,0,0}, a3 = {0,0,0,0};
  #pragma unroll 1
  for (int ch = 0; ch < 5; ++ch){
    int ks = ch*40;
    __syncthreads();
    #pragma unroll
    for (int t = 0; t < 10; ++t){
      int idx = tid + 256*t;
      int r = idx & 63, kk = idx >> 6;
      As[kk][r] = A[(m0 + r)*DE + ks + kk];
    }
    #pragma unroll
    for (int t = 0; t < 10; ++t){
      int idx = tid + 256*t;
      int r = idx & 63, kk = idx >> 6;
      int n = n0 + r;
      Es[kk][r] = (n < NENT) ? E[(size_t)n*DE + ks + kk] : 0.f;
    }
    __syncthreads();
    int rt = tid >> 4, ct = tid & 15;
    #pragma unroll 8
    for (int kk = 0; kk < 40; ++kk){
      float4 a = *(const float4*)&As[kk][rt*4];
      float4 w = *(const float4*)&Es[kk][ct*4];
      FMA16(a0,a1,a2,a3,a,w)
    }
  }
  int rt = tid >> 4, ct = tid & 15;
  int n = n0 + ct*4;
  if (n < NENT){   // NENT % 4 == 0, whole float4 valid or none
    float4 bv = *(const float4*)&bias[n];
    float4 v;
    int m = m0 + rt*4;
    v.x = sigm(a0.x+bv.x); v.y = sigm(a0.y+bv.y); v.z = sigm(a0.z+bv.z); v.w = sigm(a0.w+bv.w);
    *(float4*)&out[(size_t)(m+0)*NENT + n] = v;
    v.x = sigm(a1.x+bv.x); v.y = sigm(a1.y+bv.y); v.z = sigm(a1.z+bv.z); v.w = sigm(a1.w+bv.w);
    *(float4*)&out[(size_t)(m+1)*NENT + n] = v;
    v.x = sigm(a2.x+bv.x); v.y = sigm(a2.y+bv.y); v.z = sigm(a2.z+bv.z); v.w = sigm(a2.w+bv.w);
    *(float4*)&out[(size_t)(m+2)*NENT + n] = v;
    v.x = sigm(a3.x+bv.x); v.y = sigm(a3.y+bv.y); v.z = sigm(a3.z+bv.z); v.w = sigm(a3.w+bv.w);
    *(float4*)&out[(size_t)(m+3)*NENT + n] = v;
  }
}

extern "C" void kernel_launch(void* const* d_in, const int* in_sizes, int n_in,
                              void* d_out, int out_size, void* d_ws, size_t ws_size,
                              hipStream_t stream){
  (void)in_sizes; (void)n_in; (void)out_size; (void)ws_size;
  const float* e1    = (const float*)d_in[0];
  const float* r     = (const float*)d_in[1];
  const float* fc1_w = (const float*)d_in[2];
  const float* fc1_b = (const float*)d_in[3];
  const float* fc_w  = (const float*)d_in[4];
  const float* fc_b  = (const float*)d_in[5];
  const float* E     = (const float*)d_in[6];
  const float* bE    = (const float*)d_in[7];
  const float* g0    = (const float*)d_in[8];
  const float* b0    = (const float*)d_in[9];
  const float* g1    = (const float*)d_in[10];
  const float* b1    = (const float*)d_in[11];
  const float* g2    = (const float*)d_in[12];
  const float* b2    = (const float*)d_in[13];
  float* ws  = (float*)d_ws;
  float* out = (float*)d_out;

  k_bn0_part  <<<64,  256, 0, stream>>>(e1, ws);
  k_bn0_final <<<1,   64,  0, stream>>>(g0, b0, ws);
  k_x         <<<800, 256, 0, stream>>>(e1, ws);
  k_fc1       <<<1024,256, 0, stream>>>(r, fc1_w, fc1_b, ws);
  k_conv      <<<1024,256, 0, stream>>>(ws);
  k_bn1_final <<<32,  256, 0, stream>>>(g1, b1, ws);
  k_ygemm     <<<dim3(4,16,8), 256, 0, stream>>>(fc_w, ws);
  k_yreduce   <<<800, 256, 0, stream>>>(fc_b, ws);
  k_bn2       <<<200, 256, 0, stream>>>(g2, b2, ws);
  k_arelu     <<<800, 256, 0, stream>>>(ws);
  k_biggemm   <<<dim3(1563,16), 256, 0, stream>>>(E, bE, ws, out);
}

// Round 2
// 543.059 us; speedup vs baseline: 2.6074x; 2.6074x over previous
//
#include <hip/hip_runtime.h>
#include <math.h>

#define B_    1024
#define DE    200
#define DR    200
#define NFC   32
#define LFC   9
#define LL    192          // DE - LFC + 1
#define FC1LEN 288         // NFC*LFC
#define FCLEN 6144         // NFC*LL
#define NENT  100000
#define EPSI  1e-5f
#define KPAD  224          // K padded to 7*32 for 16x16x32 MFMA

// ---- workspace layout (float offsets) ----
#define O_S0   0           // s0,t0 (2)
#define O_P0   64          // bn0 partials: 64 blocks x 2
#define O_S1   256         // s1[32], t1[32]
#define O_S2   320         // s2[200], t2[200]
#define O_P1   768         // bn1 partials: 1024 x 32 x 2 = 65536
#define O_X    66304       // x: 1024x200
#define O_K    271104      // k: 1024x288
#define O_CONV 566016      // conv: 1024x6144
#define O_Y    6857472     // y: 1024x200
#define O_PART 7267072     // y-gemm partials: 8 x 204800
#define O_ABF  8905472     // A bf16 padded: 1024x224 ushorts = 114688 float slots
// end: 9020160 floats = 36.1 MB

typedef __attribute__((ext_vector_type(8))) short bf16x8;
typedef __attribute__((ext_vector_type(4))) float f32x4;

__device__ __forceinline__ float sigm(float x){
  return __fdividef(1.0f, 1.0f + __expf(-x));
}

__device__ __forceinline__ unsigned short f2bf(float f){
  unsigned int u = __float_as_uint(f);
  u = (u + 0x7FFFu + ((u >> 16) & 1u)) >> 16;   // RNE
  return (unsigned short)u;
}

// ---------- BN0: global mean/var of e1 ----------
__global__ void k_bn0_part(const float* __restrict__ e1, float* __restrict__ ws){
  __shared__ float ss[256], sq[256];
  int tid = threadIdx.x;
  float a = 0.f, b = 0.f;
  for (int i = blockIdx.x*256 + tid; i < B_*DE; i += 64*256){
    float v = e1[i]; a += v; b += v*v;
  }
  ss[tid]=a; sq[tid]=b; __syncthreads();
  for (int s=128; s>0; s>>=1){
    if (tid < s){ ss[tid]+=ss[tid+s]; sq[tid]+=sq[tid+s]; }
    __syncthreads();
  }
  if (tid==0){ ws[O_P0+2*blockIdx.x]=ss[0]; ws[O_P0+2*blockIdx.x+1]=sq[0]; }
}

__global__ void k_bn0_final(const float* __restrict__ g, const float* __restrict__ bt,
                            float* __restrict__ ws){
  int tid = threadIdx.x;  // 64 threads = 1 wave
  float a = ws[O_P0+2*tid], b = ws[O_P0+2*tid+1];
  for (int o=32; o>0; o>>=1){ a += __shfl_down(a,o); b += __shfl_down(b,o); }
  if (tid==0){
    float n = (float)(B_*DE);
    float m = a/n;
    float v = b/n - m*m;
    float s = rsqrtf(v + EPSI) * g[0];
    ws[O_S0]   = s;
    ws[O_S0+1] = bt[0] - m*s;
  }
}

__global__ void k_x(const float* __restrict__ e1, float* __restrict__ ws){
  float s = ws[O_S0], t = ws[O_S0+1];
  int i = blockIdx.x*256 + threadIdx.x;   // grid exactly covers 204800
  ws[O_X+i] = e1[i]*s + t;
}

// ---------- FC1: k = r @ fc1_w.T + fc1_b ----------
__global__ void k_fc1(const float* __restrict__ r, const float* __restrict__ w,
                      const float* __restrict__ bias, float* __restrict__ ws){
  __shared__ float rs[DR];
  int b = blockIdx.x;
  for (int d = threadIdx.x; d < DR; d += 256) rs[d] = r[b*DR + d];
  __syncthreads();
  for (int i = threadIdx.x; i < FC1LEN; i += 256){
    const float* wr = w + (size_t)i*DR;
    float acc = bias[i];
    #pragma unroll 4
    for (int d = 0; d < DR; ++d) acc += rs[d]*wr[d];
    ws[O_K + b*FC1LEN + i] = acc;
  }
}

// ---------- conv + bn1 partials ----------
__global__ void k_conv(float* __restrict__ ws){
  __shared__ float xs[DE];
  __shared__ float kf[FC1LEN];
  int b = blockIdx.x, tid = threadIdx.x;
  for (int d = tid; d < DE;     d += 256) xs[d] = ws[O_X + b*DE + d];
  for (int i = tid; i < FC1LEN; i += 256) kf[i] = ws[O_K + b*FC1LEN + i];
  __syncthreads();
  int f = tid >> 3, sub = tid & 7;
  float kr[LFC];
  #pragma unroll
  for (int j = 0; j < LFC; ++j) kr[j] = kf[f*LFC + j];
  float sum = 0.f, sq = 0.f;
  #pragma unroll 4
  for (int t = 0; t < 24; ++t){
    int l = sub + 8*t;
    float acc = 0.f;
    #pragma unroll
    for (int j = 0; j < LFC; ++j) acc += xs[l+j]*kr[j];
    ws[O_CONV + b*FCLEN + f*LL + l] = acc;
    sum += acc; sq += acc*acc;
  }
  for (int o = 1; o < 8; o <<= 1){ sum += __shfl_xor(sum,o); sq += __shfl_xor(sq,o); }
  if (sub == 0){
    ws[O_P1 + (b*NFC + f)*2    ] = sum;
    ws[O_P1 + (b*NFC + f)*2 + 1] = sq;
  }
}

__global__ void k_bn1_final(const float* __restrict__ g, const float* __restrict__ bt,
                            float* __restrict__ ws){
  __shared__ float ss[256], sq[256];
  int f = blockIdx.x, tid = threadIdx.x;
  float a = 0.f, b = 0.f;
  for (int i = tid; i < B_; i += 256){
    a += ws[O_P1 + (i*NFC + f)*2];
    b += ws[O_P1 + (i*NFC + f)*2 + 1];
  }
  ss[tid]=a; sq[tid]=b; __syncthreads();
  for (int s=128; s>0; s>>=1){
    if (tid < s){ ss[tid]+=ss[tid+s]; sq[tid]+=sq[tid+s]; }
    __syncthreads();
  }
  if (tid==0){
    float n = (float)(B_*LL);
    float m = ss[0]/n, v = sq[0]/n - m*m;
    float s = rsqrtf(v + EPSI) * g[f];
    ws[O_S1 + f]       = s;
    ws[O_S1 + NFC + f] = bt[f] - m*s;
  }
}

// ---------- y-GEMM (fp32, K-split 8) ----------
#define FMA16(A0,A1,A2,A3,a,w) \
  A0.x += a.x*w.x; A0.y += a.x*w.y; A0.z += a.x*w.z; A0.w += a.x*w.w; \
  A1.x += a.y*w.x; A1.y += a.y*w.y; A1.z += a.y*w.z; A1.w += a.y*w.w; \
  A2.x += a.z*w.x; A2.y += a.z*w.y; A2.z += a.z*w.z; A2.w += a.z*w.w; \
  A3.x += a.w*w.x; A3.y += a.w*w.y; A3.z += a.w*w.z; A3.w += a.w*w.w;

__global__ __launch_bounds__(256) void k_ygemm(const float* __restrict__ fcw,
                                               float* __restrict__ ws){
  __shared__ __align__(16) float As[64][64];
  __shared__ __align__(16) float Bs[64][64];
  __shared__ float s1s[2*NFC];
  const float* conv = ws + O_CONV;
  int tid = threadIdx.x;
  if (tid < 2*NFC) s1s[tid] = ws[O_S1 + tid];
  int n0 = blockIdx.x*64;
  int m0 = blockIdx.y*64;
  int seg = blockIdx.z;
  float4 a0 = {0,0,0,0}, a1 = {0,0,0,0}, a2 = {0,0,0,0}, a3 = {0,0,0,0};
  for (int ch = 0; ch < 12; ++ch){
    int ks = seg*768 + ch*64;
    __syncthreads();
    #pragma unroll
    for (int t = 0; t < 16; ++t){
      int idx = tid + 256*t;
      int r = idx & 63, kk = idx >> 6;
      int i = ks + kk;
      int f = i / LL;
      float v = conv[(size_t)(m0 + r)*FCLEN + i];
      As[kk][r] = v*s1s[f] + s1s[NFC + f];
    }
    #pragma unroll
    for (int t = 0; t < 16; ++t){
      int idx = tid + 256*t;
      int r = idx & 63, kk = idx >> 6;
      int o = n0 + r;
      Bs[kk][r] = (o < DE) ? fcw[(size_t)o*FCLEN + ks + kk] : 0.f;
    }
    __syncthreads();
    int rt = tid >> 4, ct = tid & 15;
    #pragma unroll 8
    for (int kk = 0; kk < 64; ++kk){
      float4 a = *(const float4*)&As[kk][rt*4];
      float4 w = *(const float4*)&Bs[kk][ct*4];
      FMA16(a0,a1,a2,a3,a,w)
    }
  }
  int rt = tid >> 4, ct = tid & 15;
  int o = n0 + ct*4;
  if (o < DE){
    float* part = ws + O_PART + (size_t)seg*(B_*DE);
    float4* p0 = (float4*)&part[(m0 + rt*4 + 0)*DE + o];
    float4* p1 = (float4*)&part[(m0 + rt*4 + 1)*DE + o];
    float4* p2 = (float4*)&part[(m0 + rt*4 + 2)*DE + o];
    float4* p3 = (float4*)&part[(m0 + rt*4 + 3)*DE + o];
    *p0 = a0; *p1 = a1; *p2 = a2; *p3 = a3;
  }
}

__global__ void k_yreduce(const float* __restrict__ fcb, float* __restrict__ ws){
  int i = blockIdx.x*256 + threadIdx.x;   // 204800
  int o = i % DE;
  float y = fcb[o];
  #pragma unroll
  for (int s = 0; s < 8; ++s) y += ws[O_PART + s*(B_*DE) + i];
  ws[O_Y + i] = y;
}

// ---------- BN2 stats ----------
__global__ void k_bn2(const float* __restrict__ g, const float* __restrict__ bt,
                      float* __restrict__ ws){
  __shared__ float ss[256], sq[256];
  int o = blockIdx.x, tid = threadIdx.x;
  float a = 0.f, b = 0.f;
  for (int i = tid; i < B_; i += 256){
    float v = ws[O_Y + i*DE + o];
    a += v; b += v*v;
  }
  ss[tid]=a; sq[tid]=b; __syncthreads();
  for (int s=128; s>0; s>>=1){
    if (tid < s){ ss[tid]+=ss[tid+s]; sq[tid]+=sq[tid+s]; }
    __syncthreads();
  }
  if (tid==0){
    float n = (float)B_;
    float m = ss[0]/n, v = sq[0]/n - m*m;
    float s = rsqrtf(v + EPSI) * g[o];
    ws[O_S2 + o]      = s;
    ws[O_S2 + DE + o] = bt[o] - m*s;
  }
}

// ---------- BN2-apply + ReLU + bf16 convert, K-padded to 224 ----------
__global__ void k_abf(float* __restrict__ ws){
  int i = blockIdx.x*256 + threadIdx.x;   // 0..229375  (1024*224)
  int row = i / KPAD, kk = i - row*KPAD;
  unsigned short* Abf = (unsigned short*)(ws + O_ABF);
  float v = 0.f;
  if (kk < DE){
    float y = ws[O_Y + row*DE + kk];
    v = fmaxf(y*ws[O_S2 + kk] + ws[O_S2 + DE + kk], 0.f);
  }
  Abf[i] = f2bf(v);
}

// ---------- scores GEMM: bf16 MFMA, out = sigmoid(A.E^T + b) ----------
// block: 256 thr = 4 waves; tile 64(m) x 256(n); wave tile 64x64 = 4x4 frags
__global__ __launch_bounds__(256) void k_scores(const float* __restrict__ E,
                                                const float* __restrict__ bias,
                                                const float* __restrict__ ws,
                                                float* __restrict__ out){
  const unsigned short* Abf = (const unsigned short*)(ws + O_ABF);
  int gid = blockIdx.x;                    // 6256 = 16 m-tiles * 391 n-tiles
  int swz = (gid & 7)*782 + (gid >> 3);    // bijective XCD swizzle (6256 % 8 == 0)
  int m_t = swz & 15, n_t = swz >> 4;      // m fastest: 16 consecutive share E tile
  int m0 = m_t*64;
  int lane = threadIdx.x & 63, wid = threadIdx.x >> 6;
  int n0 = n_t*256 + wid*64;
  int lr = lane & 15, lg = lane >> 4;

  f32x4 acc[4][4] = {};

  const float* ep[4];
  int ncol[4];
  #pragma unroll
  for (int nf = 0; nf < 4; ++nf){
    int n = n0 + nf*16 + lr;
    ncol[nf] = n;
    int nc = (n < NENT) ? n : (NENT-1);
    ep[nf] = E + (size_t)nc*DE + lg*8;
  }
  const unsigned short* ap = Abf + (size_t)(m0 + lr)*KPAD + lg*8;

  #pragma unroll
  for (int ks = 0; ks < 7; ++ks){
    int kb = ks*32;
    bf16x8 a[4], b[4];
    #pragma unroll
    for (int mf = 0; mf < 4; ++mf)
      a[mf] = *(const bf16x8*)(ap + (size_t)mf*16*KPAD + kb);
    bool kval = (ks < 6) || (lg == 0);     // kb + lg*8 < 200 ?
    #pragma unroll
    for (int nf = 0; nf < 4; ++nf){
      bf16x8 bb = (bf16x8){0,0,0,0,0,0,0,0};
      if (kval){
        float4 f0 = *(const float4*)(ep[nf] + kb);
        float4 f1 = *(const float4*)(ep[nf] + kb + 4);
        bb[0]=(short)f2bf(f0.x); bb[1]=(short)f2bf(f0.y);
        bb[2]=(short)f2bf(f0.z); bb[3]=(short)f2bf(f0.w);
        bb[4]=(short)f2bf(f1.x); bb[5]=(short)f2bf(f1.y);
        bb[6]=(short)f2bf(f1.z); bb[7]=(short)f2bf(f1.w);
      }
      b[nf] = bb;
    }
    #pragma unroll
    for (int mf = 0; mf < 4; ++mf)
      #pragma unroll
      for (int nf = 0; nf < 4; ++nf)
        acc[mf][nf] = __builtin_amdgcn_mfma_f32_16x16x32_bf16(a[mf], b[nf], acc[mf][nf], 0, 0, 0);
  }

  #pragma unroll
  for (int nf = 0; nf < 4; ++nf){
    int col = ncol[nf];
    if (col < NENT){
      float bv = bias[col];
      #pragma unroll
      for (int mf = 0; mf < 4; ++mf){
        int row = m0 + mf*16 + lg*4;
        #pragma unroll
        for (int r = 0; r < 4; ++r)
          out[(size_t)(row + r)*NENT + col] = sigm(acc[mf][nf][r] + bv);
      }
    }
  }
}

extern "C" void kernel_launch(void* const* d_in, const int* in_sizes, int n_in,
                              void* d_out, int out_size, void* d_ws, size_t ws_size,
                              hipStream_t stream){
  (void)in_sizes; (void)n_in; (void)out_size; (void)ws_size;
  const float* e1    = (const float*)d_in[0];
  const float* r     = (const float*)d_in[1];
  const float* fc1_w = (const float*)d_in[2];
  const float* fc1_b = (const float*)d_in[3];
  const float* fc_w  = (const float*)d_in[4];
  const float* fc_b  = (const float*)d_in[5];
  const float* E     = (const float*)d_in[6];
  const float* bE    = (const float*)d_in[7];
  const float* g0    = (const float*)d_in[8];
  const float* b0    = (const float*)d_in[9];
  const float* g1    = (const float*)d_in[10];
  const float* b1    = (const float*)d_in[11];
  const float* g2    = (const float*)d_in[12];
  const float* b2    = (const float*)d_in[13];
  float* ws  = (float*)d_ws;
  float* out = (float*)d_out;

  k_bn0_part  <<<64,  256, 0, stream>>>(e1, ws);
  k_bn0_final <<<1,   64,  0, stream>>>(g0, b0, ws);
  k_x         <<<800, 256, 0, stream>>>(e1, ws);
  k_fc1       <<<1024,256, 0, stream>>>(r, fc1_w, fc1_b, ws);
  k_conv      <<<1024,256, 0, stream>>>(ws);
  k_bn1_final <<<32,  256, 0, stream>>>(g1, b1, ws);
  k_ygemm     <<<dim3(4,16,8), 256, 0, stream>>>(fc_w, ws);
  k_yreduce   <<<800, 256, 0, stream>>>(fc_b, ws);
  k_bn2       <<<200, 256, 0, stream>>>(g2, b2, ws);
  k_abf       <<<896, 256, 0, stream>>>(ws);
  k_scores    <<<6256,256, 0, stream>>>(E, bE, ws, out);
}

// Round 3
// 441.504 us; speedup vs baseline: 3.2072x; 1.2300x over previous
//
#include <hip/hip_runtime.h>
#include <math.h>

#define B_    1024
#define DE    200
#define DR    200
#define NFC   32
#define LFC   9
#define LL    192          // DE - LFC + 1
#define FC1LEN 288         // NFC*LFC
#define FCLEN 6144         // NFC*LL
#define NENT  100000
#define EPSI  1e-5f
#define KPAD  224          // K padded to 7*32 for 16x16x32 MFMA
#define NKS   7            // KPAD/32
#define NTILES 6256        // ceil(100000/16) -> 100096 cols padded
#define NPAD  100096

// ---- workspace layout (float offsets) ----
#define O_S0   0           // s0,t0 (2)
#define O_P0   64          // bn0 partials: 64 blocks x 2
#define O_S1   256         // s1[32], t1[32]
#define O_S2   320         // s2[200], t2[200]
#define O_P1   768         // bn1 partials: 1024 x 32 x 2 = 65536
#define O_ABF  66304       // A bf16 frag layout: 64*7*64*8 bf16 = 114688 float slots (reuses dead region)
#define O_K    271104      // k: 1024x288
#define O_CONV 566016      // conv: 1024x6144 (dead after ygemm)
#define O_Y    6857472     // y: 1024x200 (dead after abf)
#define O_PART 7267072     // y-gemm partials: 8 x 204800 (dead after yreduce)
#define O_EBF  271104      // E bf16 frag layout: 6256*7*64*8 bf16 = 11202048 float slots
                           // (overlaps O_K/O_CONV/O_Y/O_PART - all dead before k_ebf runs)
// end: 271104 + 11202048 = 11473152 floats = 45.9 MB

typedef __attribute__((ext_vector_type(8))) short bf16x8;
typedef __attribute__((ext_vector_type(4))) float f32x4;

__device__ __forceinline__ float sigm(float x){
  return __fdividef(1.0f, 1.0f + __expf(-x));
}

__device__ __forceinline__ unsigned short f2bf(float f){
  unsigned int u = __float_as_uint(f);
  u = (u + 0x7FFFu + ((u >> 16) & 1u)) >> 16;   // RNE
  return (unsigned short)u;
}

// ---------- BN0: global mean/var of e1 ----------
__global__ void k_bn0_part(const float* __restrict__ e1, float* __restrict__ ws){
  __shared__ float ss[256], sq[256];
  int tid = threadIdx.x;
  float a = 0.f, b = 0.f;
  for (int i = blockIdx.x*256 + tid; i < B_*DE; i += 64*256){
    float v = e1[i]; a += v; b += v*v;
  }
  ss[tid]=a; sq[tid]=b; __syncthreads();
  for (int s=128; s>0; s>>=1){
    if (tid < s){ ss[tid]+=ss[tid+s]; sq[tid]+=sq[tid+s]; }
    __syncthreads();
  }
  if (tid==0){ ws[O_P0+2*blockIdx.x]=ss[0]; ws[O_P0+2*blockIdx.x+1]=sq[0]; }
}

__global__ void k_bn0_final(const float* __restrict__ g, const float* __restrict__ bt,
                            float* __restrict__ ws){
  int tid = threadIdx.x;  // 64 threads = 1 wave
  float a = ws[O_P0+2*tid], b = ws[O_P0+2*tid+1];
  for (int o=32; o>0; o>>=1){ a += __shfl_down(a,o); b += __shfl_down(b,o); }
  if (tid==0){
    float n = (float)(B_*DE);
    float m = a/n;
    float v = b/n - m*m;
    float s = rsqrtf(v + EPSI) * g[0];
    ws[O_S0]   = s;
    ws[O_S0+1] = bt[0] - m*s;
  }
}

// ---------- FC1: k = r @ fc1_w.T + fc1_b ----------
__global__ void k_fc1(const float* __restrict__ r, const float* __restrict__ w,
                      const float* __restrict__ bias, float* __restrict__ ws){
  __shared__ float rs[DR];
  int b = blockIdx.x;
  for (int d = threadIdx.x; d < DR; d += 256) rs[d] = r[b*DR + d];
  __syncthreads();
  for (int i = threadIdx.x; i < FC1LEN; i += 256){
    const float* wr = w + (size_t)i*DR;
    float acc = bias[i];
    #pragma unroll 4
    for (int d = 0; d < DR; ++d) acc += rs[d]*wr[d];
    ws[O_K + b*FC1LEN + i] = acc;
  }
}

// ---------- conv (BN0 applied on the fly) + bn1 partials ----------
__global__ void k_conv(const float* __restrict__ e1, float* __restrict__ ws){
  __shared__ float xs[DE];
  __shared__ float kf[FC1LEN];
  int b = blockIdx.x, tid = threadIdx.x;
  float s0v = ws[O_S0], t0v = ws[O_S0+1];
  for (int d = tid; d < DE;     d += 256) xs[d] = e1[b*DE + d]*s0v + t0v;
  for (int i = tid; i < FC1LEN; i += 256) kf[i] = ws[O_K + b*FC1LEN + i];
  __syncthreads();
  int f = tid >> 3, sub = tid & 7;
  float kr[LFC];
  #pragma unroll
  for (int j = 0; j < LFC; ++j) kr[j] = kf[f*LFC + j];
  float sum = 0.f, sq = 0.f;
  #pragma unroll 4
  for (int t = 0; t < 24; ++t){
    int l = sub + 8*t;
    float acc = 0.f;
    #pragma unroll
    for (int j = 0; j < LFC; ++j) acc += xs[l+j]*kr[j];
    ws[O_CONV + b*FCLEN + f*LL + l] = acc;
    sum += acc; sq += acc*acc;
  }
  for (int o = 1; o < 8; o <<= 1){ sum += __shfl_xor(sum,o); sq += __shfl_xor(sq,o); }
  if (sub == 0){
    ws[O_P1 + (b*NFC + f)*2    ] = sum;
    ws[O_P1 + (b*NFC + f)*2 + 1] = sq;
  }
}

__global__ void k_bn1_final(const float* __restrict__ g, const float* __restrict__ bt,
                            float* __restrict__ ws){
  __shared__ float ss[256], sq[256];
  int f = blockIdx.x, tid = threadIdx.x;
  float a = 0.f, b = 0.f;
  for (int i = tid; i < B_; i += 256){
    a += ws[O_P1 + (i*NFC + f)*2];
    b += ws[O_P1 + (i*NFC + f)*2 + 1];
  }
  ss[tid]=a; sq[tid]=b; __syncthreads();
  for (int s=128; s>0; s>>=1){
    if (tid < s){ ss[tid]+=ss[tid+s]; sq[tid]+=sq[tid+s]; }
    __syncthreads();
  }
  if (tid==0){
    float n = (float)(B_*LL);
    float m = ss[0]/n, v = sq[0]/n - m*m;
    float s = rsqrtf(v + EPSI) * g[f];
    ws[O_S1 + f]       = s;
    ws[O_S1 + NFC + f] = bt[f] - m*s;
  }
}

// ---------- y-GEMM (fp32, K-split 8) ----------
#define FMA16(A0,A1,A2,A3,a,w) \
  A0.x += a.x*w.x; A0.y += a.x*w.y; A0.z += a.x*w.z; A0.w += a.x*w.w; \
  A1.x += a.y*w.x; A1.y += a.y*w.y; A1.z += a.y*w.z; A1.w += a.y*w.w; \
  A2.x += a.z*w.x; A2.y += a.z*w.y; A2.z += a.z*w.z; A2.w += a.z*w.w; \
  A3.x += a.w*w.x; A3.y += a.w*w.y; A3.z += a.w*w.z; A3.w += a.w*w.w;

__global__ __launch_bounds__(256) void k_ygemm(const float* __restrict__ fcw,
                                               float* __restrict__ ws){
  __shared__ __align__(16) float As[64][64];
  __shared__ __align__(16) float Bs[64][64];
  __shared__ float s1s[2*NFC];
  const float* conv = ws + O_CONV;
  int tid = threadIdx.x;
  if (tid < 2*NFC) s1s[tid] = ws[O_S1 + tid];
  int n0 = blockIdx.x*64;
  int m0 = blockIdx.y*64;
  int seg = blockIdx.z;
  float4 a0 = {0,0,0,0}, a1 = {0,0,0,0}, a2 = {0,0,0,0}, a3 = {0,0,0,0};
  for (int ch = 0; ch < 12; ++ch){
    int ks = seg*768 + ch*64;
    __syncthreads();
    #pragma unroll
    for (int t = 0; t < 16; ++t){
      int idx = tid + 256*t;
      int r = idx & 63, kk = idx >> 6;
      int i = ks + kk;
      int f = i / LL;
      float v = conv[(size_t)(m0 + r)*FCLEN + i];
      As[kk][r] = v*s1s[f] + s1s[NFC + f];
    }
    #pragma unroll
    for (int t = 0; t < 16; ++t){
      int idx = tid + 256*t;
      int r = idx & 63, kk = idx >> 6;
      int o = n0 + r;
      Bs[kk][r] = (o < DE) ? fcw[(size_t)o*FCLEN + ks + kk] : 0.f;
    }
    __syncthreads();
    int rt = tid >> 4, ct = tid & 15;
    #pragma unroll 8
    for (int kk = 0; kk < 64; ++kk){
      float4 a = *(const float4*)&As[kk][rt*4];
      float4 w = *(const float4*)&Bs[kk][ct*4];
      FMA16(a0,a1,a2,a3,a,w)
    }
  }
  int rt = tid >> 4, ct = tid & 15;
  int o = n0 + ct*4;
  if (o < DE){
    float* part = ws + O_PART + (size_t)seg*(B_*DE);
    float4* p0 = (float4*)&part[(m0 + rt*4 + 0)*DE + o];
    float4* p1 = (float4*)&part[(m0 + rt*4 + 1)*DE + o];
    float4* p2 = (float4*)&part[(m0 + rt*4 + 2)*DE + o];
    float4* p3 = (float4*)&part[(m0 + rt*4 + 3)*DE + o];
    *p0 = a0; *p1 = a1; *p2 = a2; *p3 = a3;
  }
}

__global__ void k_yreduce(const float* __restrict__ fcb, float* __restrict__ ws){
  int i = blockIdx.x*256 + threadIdx.x;   // 204800
  int o = i % DE;
  float y = fcb[o];
  #pragma unroll
  for (int s = 0; s < 8; ++s) y += ws[O_PART + s*(B_*DE) + i];
  ws[O_Y + i] = y;
}

// ---------- BN2 stats ----------
__global__ void k_bn2(const float* __restrict__ g, const float* __restrict__ bt,
                      float* __restrict__ ws){
  __shared__ float ss[256], sq[256];
  int o = blockIdx.x, tid = threadIdx.x;
  float a = 0.f, b = 0.f;
  for (int i = tid; i < B_; i += 256){
    float v = ws[O_Y + i*DE + o];
    a += v; b += v*v;
  }
  ss[tid]=a; sq[tid]=b; __syncthreads();
  for (int s=128; s>0; s>>=1){
    if (tid < s){ ss[tid]+=ss[tid+s]; sq[tid]+=sq[tid+s]; }
    __syncthreads();
  }
  if (tid==0){
    float n = (float)B_;
    float m = ss[0]/n, v = sq[0]/n - m*m;
    float s = rsqrtf(v + EPSI) * g[o];
    ws[O_S2 + o]      = s;
    ws[O_S2 + DE + o] = bt[o] - m*s;
  }
}

// ---------- BN2-apply + ReLU + bf16, packed in MFMA A-fragment layout ----------
// Abf[((mtile*7+ks)*64+lane)*8+j] = A[mtile*16+(lane&15)][ks*32+(lane>>4)*8+j]
__global__ void k_abf(float* __restrict__ ws){
  int s = blockIdx.x*256 + threadIdx.x;   // 64*7*64 = 28672 slots
  int lane = s & 63;
  int ks = (s >> 6) % NKS;
  int mtile = (s >> 6) / NKS;
  int m = mtile*16 + (lane & 15);
  int k0 = ks*32 + (lane >> 4)*8;
  unsigned short o8[8];
  #pragma unroll
  for (int j = 0; j < 8; ++j){
    int k = k0 + j;
    float v = 0.f;
    if (k < DE){
      float y = ws[O_Y + m*DE + k];
      v = fmaxf(y*ws[O_S2 + k] + ws[O_S2 + DE + k], 0.f);
    }
    o8[j] = f2bf(v);
  }
  unsigned short* Abf = (unsigned short*)(ws + O_ABF);
  *(bf16x8*)(Abf + (size_t)s*8) = *(bf16x8*)o8;
}

// ---------- E -> bf16, packed in MFMA B-fragment layout ----------
// Ebf[((ntile*7+ks)*64+lane)*8+j] = E[ntile*16+(lane&15)][ks*32+(lane>>4)*8+j]
__global__ void k_ebf(const float* __restrict__ E, float* __restrict__ ws){
  int s = blockIdx.x*256 + threadIdx.x;   // 6256*7*64 = 2801152 slots (exact grid)
  int lane = s & 63;
  int ks = (s >> 6) % NKS;
  int ntile = (s >> 6) / NKS;
  int n = ntile*16 + (lane & 15);
  int k0 = ks*32 + (lane >> 4)*8;
  unsigned short o8[8];
  if (n < NENT && k0 + 8 <= DE){
    const float* ep = E + (size_t)n*DE + k0;
    float4 f0 = *(const float4*)ep;
    float4 f1 = *(const float4*)(ep + 4);
    o8[0]=f2bf(f0.x); o8[1]=f2bf(f0.y); o8[2]=f2bf(f0.z); o8[3]=f2bf(f0.w);
    o8[4]=f2bf(f1.x); o8[5]=f2bf(f1.y); o8[6]=f2bf(f1.z); o8[7]=f2bf(f1.w);
  } else {
    #pragma unroll
    for (int j = 0; j < 8; ++j){
      int k = k0 + j;
      float v = (n < NENT && k < DE) ? E[(size_t)n*DE + k] : 0.f;
      o8[j] = f2bf(v);
    }
  }
  unsigned short* Ebf = (unsigned short*)(ws + O_EBF);
  *(bf16x8*)(Ebf + (size_t)s*8) = *(bf16x8*)o8;
}

// ---------- scores GEMM: bf16 MFMA, fully coalesced fragment loads ----------
// block: 256 thr = 4 waves; tile 64(m) x 256(n); wave tile 64x64 = 4x4 frags
__global__ __launch_bounds__(256) void k_scores(const float* __restrict__ bias,
                                                const float* __restrict__ ws,
                                                float* __restrict__ out){
  const unsigned short* Abf = (const unsigned short*)(ws + O_ABF);
  const unsigned short* Ebf = (const unsigned short*)(ws + O_EBF);
  int gid = blockIdx.x;                    // 6256 = 16 m-tiles * 391 n-tiles
  int swz = (gid & 7)*782 + (gid >> 3);    // bijective XCD swizzle (6256 % 8 == 0)
  int m_t = swz & 15, n_t = swz >> 4;      // m fastest: 16 consecutive share E tile
  int m0 = m_t*64;
  int lane = threadIdx.x & 63, wid = threadIdx.x >> 6;
  int n0 = n_t*256 + wid*64;
  int mt0 = m_t*4;                         // first 16-row A tile
  int nt0 = (n0 >> 4);                     // first 16-col E tile
  int lr = lane & 15, lg = lane >> 4;

  f32x4 acc[4][4] = {};

  #pragma unroll
  for (int ks = 0; ks < NKS; ++ks){
    bf16x8 a[4], b[4];
    #pragma unroll
    for (int mf = 0; mf < 4; ++mf)
      a[mf] = *(const bf16x8*)(Abf + ((size_t)((mt0 + mf)*NKS + ks)*64 + lane)*8);
    #pragma unroll
    for (int nf = 0; nf < 4; ++nf)
      b[nf] = *(const bf16x8*)(Ebf + ((size_t)((nt0 + nf)*NKS + ks)*64 + lane)*8);
    #pragma unroll
    for (int mf = 0; mf < 4; ++mf)
      #pragma unroll
      for (int nf = 0; nf < 4; ++nf)
        acc[mf][nf] = __builtin_amdgcn_mfma_f32_16x16x32_bf16(a[mf], b[nf], acc[mf][nf], 0, 0, 0);
  }

  #pragma unroll
  for (int nf = 0; nf < 4; ++nf){
    int col = n0 + nf*16 + lr;
    if (col < NENT){
      float bv = bias[col];
      #pragma unroll
      for (int mf = 0; mf < 4; ++mf){
        int row = m0 + mf*16 + lg*4;
        #pragma unroll
        for (int r = 0; r < 4; ++r)
          out[(size_t)(row + r)*NENT + col] = sigm(acc[mf][nf][r] + bv);
      }
    }
  }
}

extern "C" void kernel_launch(void* const* d_in, const int* in_sizes, int n_in,
                              void* d_out, int out_size, void* d_ws, size_t ws_size,
                              hipStream_t stream){
  (void)in_sizes; (void)n_in; (void)out_size; (void)ws_size;
  const float* e1    = (const float*)d_in[0];
  const float* r     = (const float*)d_in[1];
  const float* fc1_w = (const float*)d_in[2];
  const float* fc1_b = (const float*)d_in[3];
  const float* fc_w  = (const float*)d_in[4];
  const float* fc_b  = (const float*)d_in[5];
  const float* E     = (const float*)d_in[6];
  const float* bE    = (const float*)d_in[7];
  const float* g0    = (const float*)d_in[8];
  const float* b0    = (const float*)d_in[9];
  const float* g1    = (const float*)d_in[10];
  const float* b1    = (const float*)d_in[11];
  const float* g2    = (const float*)d_in[12];
  const float* b2    = (const float*)d_in[13];
  float* ws  = (float*)d_ws;
  float* out = (float*)d_out;

  k_bn0_part  <<<64,  256, 0, stream>>>(e1, ws);
  k_bn0_final <<<1,   64,  0, stream>>>(g0, b0, ws);
  k_fc1       <<<1024,256, 0, stream>>>(r, fc1_w, fc1_b, ws);
  k_conv      <<<1024,256, 0, stream>>>(e1, ws);
  k_bn1_final <<<32,  256, 0, stream>>>(g1, b1, ws);
  k_ygemm     <<<dim3(4,16,8), 256, 0, stream>>>(fc_w, ws);
  k_yreduce   <<<800, 256, 0, stream>>>(fc_b, ws);
  k_bn2       <<<200, 256, 0, stream>>>(g2, b2, ws);
  k_abf       <<<112, 256, 0, stream>>>(ws);
  k_ebf       <<<10942,256, 0, stream>>>(E, ws);
  k_scores    <<<6256,256, 0, stream>>>(bE, ws, out);
}

// Round 5
// 327.206 us; speedup vs baseline: 4.3275x; 1.3493x over previous
//
#include <hip/hip_runtime.h>
#include <math.h>

#define B_    1024
#define DE    200
#define DR    200
#define NFC   32
#define LFC   9
#define LL    192          // DE - LFC + 1
#define FC1LEN 288         // NFC*LFC
#define FCLEN 6144         // NFC*LL
#define NENT  100000
#define EPSI  1e-5f
#define KPAD  224          // K padded to 7*32 for 16x16x32 MFMA
#define NKS   7            // KPAD/32
#define NTILES 6256        // 100096/16 col tiles (incl. padding tiles read by k_scores)
#define YKS   192          // FCLEN/32
#define YNT   13           // ceil(200/16)

// ---- workspace layout (float offsets). RULE: a frag region of S slots
// occupies S*8 ushorts = S*4 floats. (r4 bug: sized in slots, not floats.)
#define O_S0    0
#define O_P0    64
#define O_S1    256        // s1[32], t1[32]
#define O_S2    320        // s2[200], t2[200]
#define O_P1    768        // bn1 partials 1024*32*2 -> ends 66304
#define O_EBF   66304      // E bf16 B-frags: 6256*7*64 slots = 11210752 fl -> ends 11277056
// ---- transients INSIDE the EBF region (all dead before k_ebf runs) ----
#define O_RBF   66304      // r A-frags: 28672 slots = 114688 fl -> 180992
#define O_W1BF  180992     // fc1_w B-frags: 8064 slots = 32256 fl -> 213248
#define O_K     213248     // k fp32 1024x288 = 294912 fl -> 508160
#define O_CONVB 508160     // conv bf16 1024x6144 = 3145728 fl -> 3653888
#define O_FCWP  3653888    // fcw' B-frags: 159744 slots = 638976 fl -> 4292864
#define O_CVEC  4292864    // c[200] -> 4293120
#define O_PART  4293120    // ygemm partials 8*1024*200 = 1638400 fl -> 5931520
#define O_Y     5931520    // y 1024x200 -> 6136320   (< 11277056 OK)
// ---- after EBF ----
#define O_ABF   11277056   // A bf16 frags: 28672 slots = 114688 fl -> 11391744 (45.57 MB)

typedef __attribute__((ext_vector_type(8))) short bf16x8;
typedef __attribute__((ext_vector_type(4))) float f32x4;

__device__ __forceinline__ float sigm(float x){
  return __fdividef(1.0f, 1.0f + __expf(-x));
}

__device__ __forceinline__ unsigned short f2bf(float f){
  unsigned int u = __float_as_uint(f);
  u = (u + 0x7FFFu + ((u >> 16) & 1u)) >> 16;   // RNE
  return (unsigned short)u;
}

// ---------- BN0 ----------
__global__ void k_bn0_part(const float* __restrict__ e1, float* __restrict__ ws){
  __shared__ float ss[256], sq[256];
  int tid = threadIdx.x;
  float a = 0.f, b = 0.f;
  for (int i = blockIdx.x*256 + tid; i < B_*DE; i += 64*256){
    float v = e1[i]; a += v; b += v*v;
  }
  ss[tid]=a; sq[tid]=b; __syncthreads();
  for (int s=128; s>0; s>>=1){
    if (tid < s){ ss[tid]+=ss[tid+s]; sq[tid]+=sq[tid+s]; }
    __syncthreads();
  }
  if (tid==0){ ws[O_P0+2*blockIdx.x]=ss[0]; ws[O_P0+2*blockIdx.x+1]=sq[0]; }
}

__global__ void k_bn0_final(const float* __restrict__ g, const float* __restrict__ bt,
                            float* __restrict__ ws){
  int tid = threadIdx.x;
  float a = ws[O_P0+2*tid], b = ws[O_P0+2*tid+1];
  for (int o=32; o>0; o>>=1){ a += __shfl_down(a,o); b += __shfl_down(b,o); }
  if (tid==0){
    float n = (float)(B_*DE);
    float m = a/n, v = b/n - m*m;
    float s = rsqrtf(v + EPSI) * g[0];
    ws[O_S0]   = s;
    ws[O_S0+1] = bt[0] - m*s;
  }
}

// ---------- pack r into A-frag layout (bf16, KPAD=224) ----------
__global__ void k_rbf(const float* __restrict__ r, float* __restrict__ ws){
  int s = blockIdx.x*256 + threadIdx.x;   // 28672 slots exact
  int lane = s & 63;
  int ks = (s >> 6) % NKS;
  int mtile = (s >> 6) / NKS;
  int m = mtile*16 + (lane & 15);
  int k0 = ks*32 + (lane >> 4)*8;
  unsigned short o8[8];
  #pragma unroll
  for (int j = 0; j < 8; ++j){
    int k = k0 + j;
    o8[j] = f2bf((k < DR) ? r[m*DR + k] : 0.f);
  }
  *(bf16x8*)((unsigned short*)(ws + O_RBF) + (size_t)s*8) = *(bf16x8*)o8;
}

// ---------- pack fc1_w into B-frag layout ----------
__global__ void k_w1bf(const float* __restrict__ w, float* __restrict__ ws){
  int s = blockIdx.x*256 + threadIdx.x;   // 8064 slots (grid 32 blocks, guarded)
  if (s >= 18*NKS*64) return;
  int lane = s & 63;
  int ks = (s >> 6) % NKS;
  int ntile = (s >> 6) / NKS;
  int n = ntile*16 + (lane & 15);         // < 288
  int k0 = ks*32 + (lane >> 4)*8;
  unsigned short o8[8];
  #pragma unroll
  for (int j = 0; j < 8; ++j){
    int k = k0 + j;
    o8[j] = f2bf((k < DR) ? w[(size_t)n*DR + k] : 0.f);
  }
  *(bf16x8*)((unsigned short*)(ws + O_W1BF) + (size_t)s*8) = *(bf16x8*)o8;
}

// ---------- FC1 via MFMA: k = r @ fc1_w.T + fc1_b (fp32 out) ----------
__global__ void k_fc1m(const float* __restrict__ bias, float* __restrict__ ws){
  const unsigned short* Rb = (const unsigned short*)(ws + O_RBF);
  const unsigned short* Wb = (const unsigned short*)(ws + O_W1BF);
  int mt = blockIdx.x;        // 0..15
  int nt = blockIdx.y;        // 0..17
  int lane = threadIdx.x;
  int lr = lane & 15, lg = lane >> 4;
  f32x4 acc[4] = {};
  #pragma unroll
  for (int ks = 0; ks < NKS; ++ks){
    bf16x8 b = *(const bf16x8*)(Wb + ((size_t)(nt*NKS + ks)*64 + lane)*8);
    #pragma unroll
    for (int mf = 0; mf < 4; ++mf){
      bf16x8 a = *(const bf16x8*)(Rb + ((size_t)((mt*4+mf)*NKS + ks)*64 + lane)*8);
      acc[mf] = __builtin_amdgcn_mfma_f32_16x16x32_bf16(a, b, acc[mf], 0, 0, 0);
    }
  }
  int col = nt*16 + lr;
  float bv = bias[col];
  #pragma unroll
  for (int mf = 0; mf < 4; ++mf){
    int row = mt*64 + mf*16 + lg*4;
    #pragma unroll
    for (int r = 0; r < 4; ++r)
      ws[O_K + (size_t)(row + r)*FC1LEN + col] = acc[mf][r] + bv;
  }
}

// ---------- conv (BN0 on the fly) -> bf16 + bn1 partials ----------
__global__ void k_conv(const float* __restrict__ e1, float* __restrict__ ws){
  __shared__ float xs[DE];
  __shared__ float kf[FC1LEN];
  int b = blockIdx.x, tid = threadIdx.x;
  float s0v = ws[O_S0], t0v = ws[O_S0+1];
  for (int d = tid; d < DE;     d += 256) xs[d] = e1[b*DE + d]*s0v + t0v;
  for (int i = tid; i < FC1LEN; i += 256) kf[i] = ws[O_K + (size_t)b*FC1LEN + i];
  __syncthreads();
  unsigned short* convb = (unsigned short*)(ws + O_CONVB);
  int f = tid >> 3, sub = tid & 7;
  float kr[LFC];
  #pragma unroll
  for (int j = 0; j < LFC; ++j) kr[j] = kf[f*LFC + j];
  float sum = 0.f, sq = 0.f;
  #pragma unroll 4
  for (int t = 0; t < 24; ++t){
    int l = sub + 8*t;
    float acc = 0.f;
    #pragma unroll
    for (int j = 0; j < LFC; ++j) acc += xs[l+j]*kr[j];
    convb[(size_t)b*FCLEN + f*LL + l] = f2bf(acc);
    sum += acc; sq += acc*acc;
  }
  for (int o = 1; o < 8; o <<= 1){ sum += __shfl_xor(sum,o); sq += __shfl_xor(sq,o); }
  if (sub == 0){
    ws[O_P1 + (b*NFC + f)*2    ] = sum;
    ws[O_P1 + (b*NFC + f)*2 + 1] = sq;
  }
}

__global__ void k_bn1_final(const float* __restrict__ g, const float* __restrict__ bt,
                            float* __restrict__ ws){
  __shared__ float ss[256], sq[256];
  int f = blockIdx.x, tid = threadIdx.x;
  float a = 0.f, b = 0.f;
  for (int i = tid; i < B_; i += 256){
    a += ws[O_P1 + (i*NFC + f)*2];
    b += ws[O_P1 + (i*NFC + f)*2 + 1];
  }
  ss[tid]=a; sq[tid]=b; __syncthreads();
  for (int s=128; s>0; s>>=1){
    if (tid < s){ ss[tid]+=ss[tid+s]; sq[tid]+=sq[tid+s]; }
    __syncthreads();
  }
  if (tid==0){
    float n = (float)(B_*LL);
    float m = ss[0]/n, v = sq[0]/n - m*m;
    float s = rsqrtf(v + EPSI) * g[f];
    ws[O_S1 + f]       = s;
    ws[O_S1 + NFC + f] = bt[f] - m*s;
  }
}

// ---------- pack fcw*s1[f] into B-frag layout (bf16) ----------
__global__ void k_fcwp(const float* __restrict__ fcw, float* __restrict__ ws){
  int s = blockIdx.x*256 + threadIdx.x;   // 159744 slots exact (624 blocks)
  int lane = s & 63;
  int ks = (s >> 6) % YKS;
  int ntile = (s >> 6) / YKS;
  int n = ntile*16 + (lane & 15);         // < 208
  int k0 = ks*32 + (lane >> 4)*8;         // < 6144
  int f = (k0 >> 6) / 3;                  // k0/192, constant across the 8 elems
  float sc = ws[O_S1 + f];
  unsigned short o8[8];
  if (n < DE){
    const float* p = fcw + (size_t)n*FCLEN + k0;
    float4 f0 = *(const float4*)p;
    float4 f1 = *(const float4*)(p + 4);
    o8[0]=f2bf(f0.x*sc); o8[1]=f2bf(f0.y*sc); o8[2]=f2bf(f0.z*sc); o8[3]=f2bf(f0.w*sc);
    o8[4]=f2bf(f1.x*sc); o8[5]=f2bf(f1.y*sc); o8[6]=f2bf(f1.z*sc); o8[7]=f2bf(f1.w*sc);
  } else {
    #pragma unroll
    for (int j = 0; j < 8; ++j) o8[j] = 0;
  }
  *(bf16x8*)((unsigned short*)(ws + O_FCWP) + (size_t)s*8) = *(bf16x8*)o8;
}

// ---------- c[o] = sum_i t1[f(i)]*fcw[o,i] + fc_b[o] ----------
__global__ void k_cvec(const float* __restrict__ fcw, const float* __restrict__ fcb,
                       float* __restrict__ ws){
  __shared__ float t1s[NFC];
  __shared__ float red[256];
  int o = blockIdx.x, tid = threadIdx.x;
  if (tid < NFC) t1s[tid] = ws[O_S1 + NFC + tid];
  __syncthreads();
  float acc = 0.f;
  for (int i = tid; i < FCLEN; i += 256)
    acc += fcw[(size_t)o*FCLEN + i] * t1s[i/LL];
  red[tid] = acc; __syncthreads();
  for (int s=128; s>0; s>>=1){
    if (tid < s) red[tid] += red[tid+s];
    __syncthreads();
  }
  if (tid==0) ws[O_CVEC + o] = red[0] + fcb[o];
}

// ---------- y-GEMM via MFMA: part[seg] = convb @ fcwp^T  (K-split 8) ----------
__global__ void k_ygemm_m(float* __restrict__ ws){
  const unsigned short* Cb = (const unsigned short*)(ws + O_CONVB);
  const unsigned short* Wb = (const unsigned short*)(ws + O_FCWP);
  int mt = blockIdx.x;      // 0..15
  int nt = blockIdx.y;      // 0..12
  int seg = blockIdx.z;     // 0..7
  int lane = threadIdx.x;
  int lr = lane & 15, lg = lane >> 4;
  f32x4 acc[4] = {};
  #pragma unroll 4
  for (int ksl = 0; ksl < 24; ++ksl){
    int k = seg*768 + ksl*32 + lg*8;
    bf16x8 b = *(const bf16x8*)(Wb + ((size_t)(nt*YKS + seg*24 + ksl)*64 + lane)*8);
    #pragma unroll
    for (int mf = 0; mf < 4; ++mf){
      int m = mt*64 + mf*16 + lr;
      bf16x8 a = *(const bf16x8*)(Cb + (size_t)m*FCLEN + k);
      acc[mf] = __builtin_amdgcn_mfma_f32_16x16x32_bf16(a, b, acc[mf], 0, 0, 0);
    }
  }
  int col = nt*16 + lr;
  if (col < DE){
    float* part = ws + O_PART + (size_t)seg*(B_*DE);
    #pragma unroll
    for (int mf = 0; mf < 4; ++mf){
      int row = mt*64 + mf*16 + lg*4;
      #pragma unroll
      for (int r = 0; r < 4; ++r)
        part[(size_t)(row + r)*DE + col] = acc[mf][r];
    }
  }
}

__global__ void k_yreduce(float* __restrict__ ws){
  int i = blockIdx.x*256 + threadIdx.x;   // 204800
  int o = i % DE;
  float y = ws[O_CVEC + o];
  #pragma unroll
  for (int s = 0; s < 8; ++s) y += ws[O_PART + s*(B_*DE) + i];
  ws[O_Y + i] = y;
}

// ---------- BN2 stats ----------
__global__ void k_bn2(const float* __restrict__ g, const float* __restrict__ bt,
                      float* __restrict__ ws){
  __shared__ float ss[256], sq[256];
  int o = blockIdx.x, tid = threadIdx.x;
  float a = 0.f, b = 0.f;
  for (int i = tid; i < B_; i += 256){
    float v = ws[O_Y + i*DE + o];
    a += v; b += v*v;
  }
  ss[tid]=a; sq[tid]=b; __syncthreads();
  for (int s=128; s>0; s>>=1){
    if (tid < s){ ss[tid]+=ss[tid+s]; sq[tid]+=sq[tid+s]; }
    __syncthreads();
  }
  if (tid==0){
    float n = (float)B_;
    float m = ss[0]/n, v = sq[0]/n - m*m;
    float s = rsqrtf(v + EPSI) * g[o];
    ws[O_S2 + o]      = s;
    ws[O_S2 + DE + o] = bt[o] - m*s;
  }
}

// ---------- BN2-apply + ReLU + bf16 A-frags ----------
__global__ void k_abf(float* __restrict__ ws){
  int s = blockIdx.x*256 + threadIdx.x;   // 28672 slots exact
  int lane = s & 63;
  int ks = (s >> 6) % NKS;
  int mtile = (s >> 6) / NKS;
  int m = mtile*16 + (lane & 15);
  int k0 = ks*32 + (lane >> 4)*8;
  unsigned short o8[8];
  #pragma unroll
  for (int j = 0; j < 8; ++j){
    int k = k0 + j;
    float v = 0.f;
    if (k < DE){
      float y = ws[O_Y + m*DE + k];
      v = fmaxf(y*ws[O_S2 + k] + ws[O_S2 + DE + k], 0.f);
    }
    o8[j] = f2bf(v);
  }
  *(bf16x8*)((unsigned short*)(ws + O_ABF) + (size_t)s*8) = *(bf16x8*)o8;
}

// ---------- E -> bf16 B-frags (covers ALL 6256 tiles incl. padding) ----------
__global__ void k_ebf(const float* __restrict__ E, float* __restrict__ ws){
  int s = blockIdx.x*256 + threadIdx.x;   // 6256*7*64 = 2802688 slots (10948 blocks exact)
  int lane = s & 63;
  int ks = (s >> 6) % NKS;
  int ntile = (s >> 6) / NKS;
  int n = ntile*16 + (lane & 15);
  int k0 = ks*32 + (lane >> 4)*8;
  unsigned short o8[8];
  if (n < NENT && k0 + 8 <= DE){
    const float* ep = E + (size_t)n*DE + k0;
    float4 f0 = *(const float4*)ep;
    float4 f1 = *(const float4*)(ep + 4);
    o8[0]=f2bf(f0.x); o8[1]=f2bf(f0.y); o8[2]=f2bf(f0.z); o8[3]=f2bf(f0.w);
    o8[4]=f2bf(f1.x); o8[5]=f2bf(f1.y); o8[6]=f2bf(f1.z); o8[7]=f2bf(f1.w);
  } else {
    #pragma unroll
    for (int j = 0; j < 8; ++j){
      int k = k0 + j;
      o8[j] = f2bf((n < NENT && k < DE) ? E[(size_t)n*DE + k] : 0.f);
    }
  }
  *(bf16x8*)((unsigned short*)(ws + O_EBF) + (size_t)s*8) = *(bf16x8*)o8;
}

// ---------- scores GEMM: bf16 MFMA, 2-deep register pipeline ----------
__global__ __launch_bounds__(256) void k_scores(const float* __restrict__ bias,
                                                const float* __restrict__ ws,
                                                float* __restrict__ out){
  const unsigned short* Abf = (const unsigned short*)(ws + O_ABF);
  const unsigned short* Ebf = (const unsigned short*)(ws + O_EBF);
  int gid = blockIdx.x;                    // 6256 = 16 m-tiles * 391 n-tiles
  int swz = (gid & 7)*782 + (gid >> 3);    // bijective XCD swizzle
  int m_t = swz & 15, n_t = swz >> 4;      // m fastest: 16 consecutive share E tile
  int m0 = m_t*64;
  int lane = threadIdx.x & 63, wid = threadIdx.x >> 6;
  int n0 = n_t*256 + wid*64;
  int lr = lane & 15, lg = lane >> 4;
  const unsigned short* aB = Abf + (size_t)(m_t*4)*NKS*512 + lane*8;
  const unsigned short* bB = Ebf + (size_t)(n0 >> 4)*NKS*512 + lane*8;

  f32x4 acc[4][4] = {};
  bf16x8 aC[4], bC[4], aN[4], bN[4];
  #pragma unroll
  for (int mf = 0; mf < 4; ++mf) aC[mf] = *(const bf16x8*)(aB + (size_t)mf*NKS*512);
  #pragma unroll
  for (int nf = 0; nf < 4; ++nf) bC[nf] = *(const bf16x8*)(bB + (size_t)nf*NKS*512);

  #pragma unroll
  for (int ks = 0; ks < NKS; ++ks){
    if (ks < NKS-1){
      #pragma unroll
      for (int mf = 0; mf < 4; ++mf)
        aN[mf] = *(const bf16x8*)(aB + (size_t)mf*NKS*512 + (ks+1)*512);
      #pragma unroll
      for (int nf = 0; nf < 4; ++nf)
        bN[nf] = *(const bf16x8*)(bB + (size_t)nf*NKS*512 + (ks+1)*512);
    }
    #pragma unroll
    for (int mf = 0; mf < 4; ++mf)
      #pragma unroll
      for (int nf = 0; nf < 4; ++nf)
        acc[mf][nf] = __builtin_amdgcn_mfma_f32_16x16x32_bf16(aC[mf], bC[nf], acc[mf][nf], 0, 0, 0);
    #pragma unroll
    for (int mf = 0; mf < 4; ++mf) aC[mf] = aN[mf];
    #pragma unroll
    for (int nf = 0; nf < 4; ++nf) bC[nf] = bN[nf];
  }

  #pragma unroll
  for (int nf = 0; nf < 4; ++nf){
    int col = n0 + nf*16 + lr;
    if (col < NENT){
      float bv = bias[col];
      #pragma unroll
      for (int mf = 0; mf < 4; ++mf){
        int row = m0 + mf*16 + lg*4;
        #pragma unroll
        for (int r = 0; r < 4; ++r)
          out[(size_t)(row + r)*NENT + col] = sigm(acc[mf][nf][r] + bv);
      }
    }
  }
}

extern "C" void kernel_launch(void* const* d_in, const int* in_sizes, int n_in,
                              void* d_out, int out_size, void* d_ws, size_t ws_size,
                              hipStream_t stream){
  (void)in_sizes; (void)n_in; (void)out_size; (void)ws_size;
  const float* e1    = (const float*)d_in[0];
  const float* r     = (const float*)d_in[1];
  const float* fc1_w = (const float*)d_in[2];
  const float* fc1_b = (const float*)d_in[3];
  const float* fc_w  = (const float*)d_in[4];
  const float* fc_b  = (const float*)d_in[5];
  const float* E     = (const float*)d_in[6];
  const float* bE    = (const float*)d_in[7];
  const float* g0    = (const float*)d_in[8];
  const float* b0    = (const float*)d_in[9];
  const float* g1    = (const float*)d_in[10];
  const float* b1    = (const float*)d_in[11];
  const float* g2    = (const float*)d_in[12];
  const float* b2    = (const float*)d_in[13];
  float* ws  = (float*)d_ws;
  float* out = (float*)d_out;

  k_bn0_part  <<<64,  256, 0, stream>>>(e1, ws);
  k_bn0_final <<<1,   64,  0, stream>>>(g0, b0, ws);
  k_rbf       <<<112, 256, 0, stream>>>(r, ws);
  k_w1bf      <<<32,  256, 0, stream>>>(fc1_w, ws);
  k_fc1m      <<<dim3(16,18), 64, 0, stream>>>(fc1_b, ws);
  k_conv      <<<1024,256, 0, stream>>>(e1, ws);
  k_bn1_final <<<32,  256, 0, stream>>>(g1, b1, ws);
  k_fcwp      <<<624, 256, 0, stream>>>(fc_w, ws);
  k_cvec      <<<200, 256, 0, stream>>>(fc_w, fc_b, ws);
  k_ygemm_m   <<<dim3(16,13,8), 64, 0, stream>>>(ws);
  k_yreduce   <<<800, 256, 0, stream>>>(ws);
  k_bn2       <<<200, 256, 0, stream>>>(g2, b2, ws);
  k_abf       <<<112, 256, 0, stream>>>(ws);
  k_ebf       <<<10948,256, 0, stream>>>(E, ws);
  k_scores    <<<6256,256, 0, stream>>>(bE, ws, out);
}

// Round 6
// 295.683 us; speedup vs baseline: 4.7889x; 1.1066x over previous
//
#include <hip/hip_runtime.h>
#include <math.h>

#define B_    1024
#define DE    200
#define DR    200
#define NFC   32
#define LFC   9
#define LL    192          // DE - LFC + 1
#define FC1LEN 288         // NFC*LFC
#define FCLEN 6144         // NFC*LL
#define NENT  100000
#define EPSI  1e-5f
#define KPAD  224          // 7*32 for 16x16x32 MFMA
#define NKS   7            // KPAD/32
#define NTILES 6256        // 100096/16 col tiles
#define YKS   192          // FCLEN/32
#define YSEG  16           // K-split for y-GEMM

// ---- workspace layout (float offsets). frag region of S slots = S*4 floats ----
#define O_S0    0
#define O_P0    64
#define O_S1    256        // s1[32], t1[32]
#define O_S2    320        // s2[200], t2[200]
#define O_P1    768        // bn1 partials 1024*32*2 -> ends 66304
#define O_EBF   66304      // E B-frags: 6256*7*64 slots = 11210752 fl -> ends 11277056
// ---- transients INSIDE EBF region (dead before k_ebf) ----
#define O_RBF   66304      // r A-frags: 28672 slots = 114688 fl -> 180992
#define O_W1BF  180992     // fc1_w B-frags: 8064 slots = 32256 fl -> 213248
#define O_K     213248     // k fp32 1024x288 -> 508160
#define O_CFRAG 508160     // conv bf16 A-frags: 64*192*64 slots = 3145728 fl -> 3653888
#define O_FCWP  3653888    // fcw' B-frags: 16*192*64 slots = 786432 fl -> 4440320
#define O_CVEC  4440320    // c[200] -> 4440576
#define O_PART  4440576    // ygemm partials 16*1024*200 = 3276800 fl -> 7717376
#define O_Y     7717376    // y 1024x200 -> 7922176  (< 11277056 OK)
// ---- after EBF ----
#define O_ABF   11277056   // A frags: 28672 slots = 114688 fl -> 11391744 (45.57 MB)

typedef __attribute__((ext_vector_type(8))) short bf16x8;
typedef __attribute__((ext_vector_type(4))) float f32x4;

__device__ __forceinline__ float sigm(float x){
  return __fdividef(1.0f, 1.0f + __expf(-x));
}

__device__ __forceinline__ unsigned short f2bf(float f){
  unsigned int u = __float_as_uint(f);
  u = (u + 0x7FFFu + ((u >> 16) & 1u)) >> 16;   // RNE
  return (unsigned short)u;
}

// ---------- BN0 ----------
__global__ void k_bn0_part(const float* __restrict__ e1, float* __restrict__ ws){
  __shared__ float ss[256], sq[256];
  int tid = threadIdx.x;
  float a = 0.f, b = 0.f;
  for (int i = blockIdx.x*256 + tid; i < B_*DE; i += 64*256){
    float v = e1[i]; a += v; b += v*v;
  }
  ss[tid]=a; sq[tid]=b; __syncthreads();
  for (int s=128; s>0; s>>=1){
    if (tid < s){ ss[tid]+=ss[tid+s]; sq[tid]+=sq[tid+s]; }
    __syncthreads();
  }
  if (tid==0){ ws[O_P0+2*blockIdx.x]=ss[0]; ws[O_P0+2*blockIdx.x+1]=sq[0]; }
}

__global__ void k_bn0_final(const float* __restrict__ g, const float* __restrict__ bt,
                            float* __restrict__ ws){
  int tid = threadIdx.x;
  float a = ws[O_P0+2*tid], b = ws[O_P0+2*tid+1];
  for (int o=32; o>0; o>>=1){ a += __shfl_down(a,o); b += __shfl_down(b,o); }
  if (tid==0){
    float n = (float)(B_*DE);
    float m = a/n, v = b/n - m*m;
    float s = rsqrtf(v + EPSI) * g[0];
    ws[O_S0]   = s;
    ws[O_S0+1] = bt[0] - m*s;
  }
}

// ---------- pack r into A-frag layout ----------
__global__ void k_rbf(const float* __restrict__ r, float* __restrict__ ws){
  int s = blockIdx.x*256 + threadIdx.x;   // 28672 slots exact
  int lane = s & 63;
  int ks = (s >> 6) % NKS;
  int mtile = (s >> 6) / NKS;
  int m = mtile*16 + (lane & 15);
  int k0 = ks*32 + (lane >> 4)*8;
  unsigned short o8[8];
  #pragma unroll
  for (int j = 0; j < 8; ++j){
    int k = k0 + j;
    o8[j] = f2bf((k < DR) ? r[m*DR + k] : 0.f);
  }
  *(bf16x8*)((unsigned short*)(ws + O_RBF) + (size_t)s*8) = *(bf16x8*)o8;
}

// ---------- pack fc1_w into B-frag layout ----------
__global__ void k_w1bf(const float* __restrict__ w, float* __restrict__ ws){
  int s = blockIdx.x*256 + threadIdx.x;   // 8064 slots (32 blocks, guarded)
  if (s >= 18*NKS*64) return;
  int lane = s & 63;
  int ks = (s >> 6) % NKS;
  int ntile = (s >> 6) / NKS;
  int n = ntile*16 + (lane & 15);         // < 288
  int k0 = ks*32 + (lane >> 4)*8;
  unsigned short o8[8];
  #pragma unroll
  for (int j = 0; j < 8; ++j){
    int k = k0 + j;
    o8[j] = f2bf((k < DR) ? w[(size_t)n*DR + k] : 0.f);
  }
  *(bf16x8*)((unsigned short*)(ws + O_W1BF) + (size_t)s*8) = *(bf16x8*)o8;
}

// ---------- FC1 via MFMA ----------
__global__ void k_fc1m(const float* __restrict__ bias, float* __restrict__ ws){
  const unsigned short* Rb = (const unsigned short*)(ws + O_RBF);
  const unsigned short* Wb = (const unsigned short*)(ws + O_W1BF);
  int mt = blockIdx.x;        // 0..15
  int nt = blockIdx.y;        // 0..17
  int lane = threadIdx.x;
  int lr = lane & 15, lg = lane >> 4;
  f32x4 acc[4] = {};
  #pragma unroll
  for (int ks = 0; ks < NKS; ++ks){
    bf16x8 b = *(const bf16x8*)(Wb + ((size_t)(nt*NKS + ks)*64 + lane)*8);
    #pragma unroll
    for (int mf = 0; mf < 4; ++mf){
      bf16x8 a = *(const bf16x8*)(Rb + ((size_t)((mt*4+mf)*NKS + ks)*64 + lane)*8);
      acc[mf] = __builtin_amdgcn_mfma_f32_16x16x32_bf16(a, b, acc[mf], 0, 0, 0);
    }
  }
  int col = nt*16 + lr;
  float bv = bias[col];
  #pragma unroll
  for (int mf = 0; mf < 4; ++mf){
    int row = mt*64 + mf*16 + lg*4;
    #pragma unroll
    for (int r = 0; r < 4; ++r)
      ws[O_K + (size_t)(row + r)*FC1LEN + col] = acc[mf][r] + bv;
  }
}

// ---------- conv (BN0 on the fly) -> bf16 A-frag layout + bn1 partials ----------
__global__ void k_conv(const float* __restrict__ e1, float* __restrict__ ws){
  __shared__ float xs[DE];
  __shared__ float kf[FC1LEN];
  int b = blockIdx.x, tid = threadIdx.x;
  float s0v = ws[O_S0], t0v = ws[O_S0+1];
  for (int d = tid; d < DE;     d += 256) xs[d] = e1[b*DE + d]*s0v + t0v;
  for (int i = tid; i < FC1LEN; i += 256) kf[i] = ws[O_K + (size_t)b*FC1LEN + i];
  __syncthreads();
  unsigned short* Cf = (unsigned short*)(ws + O_CFRAG);
  int f = tid >> 3, sub = tid & 7;
  int mtile = b >> 4, mlan = b & 15;
  float kr[LFC];
  #pragma unroll
  for (int j = 0; j < LFC; ++j) kr[j] = kf[f*LFC + j];
  float sum = 0.f, sq = 0.f;
  #pragma unroll
  for (int g = 0; g < 3; ++g){
    unsigned short o8[8];
    int l0 = sub*24 + g*8;
    #pragma unroll
    for (int t = 0; t < 8; ++t){
      int l = l0 + t;
      float acc = 0.f;
      #pragma unroll
      for (int j = 0; j < LFC; ++j) acc += xs[l+j]*kr[j];
      o8[t] = f2bf(acc);
      sum += acc; sq += acc*acc;
    }
    int k0 = f*LL + l0;                     // multiple of 8
    int ks = k0 >> 5;
    int lane_w = ((k0 >> 3) & 3)*16 + mlan;
    size_t slot = (size_t)(mtile*YKS + ks)*64 + lane_w;
    *(bf16x8*)(Cf + slot*8) = *(bf16x8*)o8;
  }
  for (int o = 1; o < 8; o <<= 1){ sum += __shfl_xor(sum,o); sq += __shfl_xor(sq,o); }
  if (sub == 0){
    ws[O_P1 + (b*NFC + f)*2    ] = sum;
    ws[O_P1 + (b*NFC + f)*2 + 1] = sq;
  }
}

__global__ void k_bn1_final(const float* __restrict__ g, const float* __restrict__ bt,
                            float* __restrict__ ws){
  __shared__ float ss[256], sq[256];
  int f = blockIdx.x, tid = threadIdx.x;
  float a = 0.f, b = 0.f;
  for (int i = tid; i < B_; i += 256){
    a += ws[O_P1 + (i*NFC + f)*2];
    b += ws[O_P1 + (i*NFC + f)*2 + 1];
  }
  ss[tid]=a; sq[tid]=b; __syncthreads();
  for (int s=128; s>0; s>>=1){
    if (tid < s){ ss[tid]+=ss[tid+s]; sq[tid]+=sq[tid+s]; }
    __syncthreads();
  }
  if (tid==0){
    float n = (float)(B_*LL);
    float m = ss[0]/n, v = sq[0]/n - m*m;
    float s = rsqrtf(v + EPSI) * g[f];
    ws[O_S1 + f]       = s;
    ws[O_S1 + NFC + f] = bt[f] - m*s;
  }
}

// ---------- pack fcw*s1[f] into B-frag layout (16 n-tiles, padded) ----------
__global__ void k_fcwp(const float* __restrict__ fcw, float* __restrict__ ws){
  int s = blockIdx.x*256 + threadIdx.x;   // 16*192*64 = 196608 slots (768 blocks)
  int lane = s & 63;
  int ks = (s >> 6) % YKS;
  int ntile = (s >> 6) / YKS;
  int n = ntile*16 + (lane & 15);         // < 256
  int k0 = ks*32 + (lane >> 4)*8;         // < 6144
  int f = (k0 >> 6) / 3;                  // k0/192
  float sc = ws[O_S1 + f];
  unsigned short o8[8];
  if (n < DE){
    const float* p = fcw + (size_t)n*FCLEN + k0;
    float4 f0 = *(const float4*)p;
    float4 f1 = *(const float4*)(p + 4);
    o8[0]=f2bf(f0.x*sc); o8[1]=f2bf(f0.y*sc); o8[2]=f2bf(f0.z*sc); o8[3]=f2bf(f0.w*sc);
    o8[4]=f2bf(f1.x*sc); o8[5]=f2bf(f1.y*sc); o8[6]=f2bf(f1.z*sc); o8[7]=f2bf(f1.w*sc);
  } else {
    #pragma unroll
    for (int j = 0; j < 8; ++j) o8[j] = 0;
  }
  *(bf16x8*)((unsigned short*)(ws + O_FCWP) + (size_t)s*8) = *(bf16x8*)o8;
}

// ---------- c[o] = sum_i t1[f(i)]*fcw[o,i] + fc_b[o] ----------
__global__ void k_cvec(const float* __restrict__ fcw, const float* __restrict__ fcb,
                       float* __restrict__ ws){
  __shared__ float t1s[NFC];
  __shared__ float red[256];
  int o = blockIdx.x, tid = threadIdx.x;
  if (tid < NFC) t1s[tid] = ws[O_S1 + NFC + tid];
  __syncthreads();
  float acc = 0.f;
  for (int i = tid; i < FCLEN; i += 256)
    acc += fcw[(size_t)o*FCLEN + i] * t1s[i/LL];
  red[tid] = acc; __syncthreads();
  for (int s=128; s>0; s>>=1){
    if (tid < s) red[tid] += red[tid+s];
    __syncthreads();
  }
  if (tid==0) ws[O_CVEC + o] = red[0] + fcb[o];
}

// ---------- y-GEMM via MFMA, both sides frag-coalesced, 16-way K-split ----------
__global__ __launch_bounds__(256) void k_ygemm_m(float* __restrict__ ws){
  const unsigned short* Cb = (const unsigned short*)(ws + O_CFRAG);
  const unsigned short* Wb = (const unsigned short*)(ws + O_FCWP);
  int mt = blockIdx.x;      // 0..15 (64-row)
  int seg = blockIdx.y;     // 0..15 (12 ks each)
  int tid = threadIdx.x;
  int lane = tid & 63, wid = tid >> 6;
  int lr = lane & 15, lg = lane >> 4;
  f32x4 acc[4][4] = {};     // [mf][nf], nt = wid*4+nf
  #pragma unroll 4
  for (int ksl = 0; ksl < 12; ++ksl){
    int ks = seg*12 + ksl;
    bf16x8 a[4], bfr[4];
    #pragma unroll
    for (int mf = 0; mf < 4; ++mf)
      a[mf] = *(const bf16x8*)(Cb + ((size_t)((mt*4+mf)*YKS + ks)*64 + lane)*8);
    #pragma unroll
    for (int nf = 0; nf < 4; ++nf){
      int nt = wid*4 + nf;
      bfr[nf] = *(const bf16x8*)(Wb + ((size_t)(nt*YKS + ks)*64 + lane)*8);
    }
    #pragma unroll
    for (int mf = 0; mf < 4; ++mf)
      #pragma unroll
      for (int nf = 0; nf < 4; ++nf)
        acc[mf][nf] = __builtin_amdgcn_mfma_f32_16x16x32_bf16(a[mf], bfr[nf], acc[mf][nf], 0, 0, 0);
  }
  float* part = ws + O_PART + (size_t)seg*(B_*DE);
  #pragma unroll
  for (int nf = 0; nf < 4; ++nf){
    int col = (wid*4 + nf)*16 + lr;
    if (col < DE){
      #pragma unroll
      for (int mf = 0; mf < 4; ++mf){
        int row = mt*64 + mf*16 + lg*4;
        #pragma unroll
        for (int r = 0; r < 4; ++r)
          part[(size_t)(row + r)*DE + col] = acc[mf][nf][r];
      }
    }
  }
}

__global__ void k_yreduce(float* __restrict__ ws){
  int i = blockIdx.x*256 + threadIdx.x;   // 204800
  int o = i % DE;
  float y = ws[O_CVEC + o];
  #pragma unroll
  for (int s = 0; s < YSEG; ++s) y += ws[O_PART + (size_t)s*(B_*DE) + i];
  ws[O_Y + i] = y;
}

// ---------- BN2 stats ----------
__global__ void k_bn2(const float* __restrict__ g, const float* __restrict__ bt,
                      float* __restrict__ ws){
  __shared__ float ss[256], sq[256];
  int o = blockIdx.x, tid = threadIdx.x;
  float a = 0.f, b = 0.f;
  for (int i = tid; i < B_; i += 256){
    float v = ws[O_Y + i*DE + o];
    a += v; b += v*v;
  }
  ss[tid]=a; sq[tid]=b; __syncthreads();
  for (int s=128; s>0; s>>=1){
    if (tid < s){ ss[tid]+=ss[tid+s]; sq[tid]+=sq[tid+s]; }
    __syncthreads();
  }
  if (tid==0){
    float n = (float)B_;
    float m = ss[0]/n, v = sq[0]/n - m*m;
    float s = rsqrtf(v + EPSI) * g[o];
    ws[O_S2 + o]      = s;
    ws[O_S2 + DE + o] = bt[o] - m*s;
  }
}

// ---------- BN2-apply + ReLU + bf16 A-frags ----------
__global__ void k_abf(float* __restrict__ ws){
  int s = blockIdx.x*256 + threadIdx.x;   // 28672 slots exact
  int lane = s & 63;
  int ks = (s >> 6) % NKS;
  int mtile = (s >> 6) / NKS;
  int m = mtile*16 + (lane & 15);
  int k0 = ks*32 + (lane >> 4)*8;
  unsigned short o8[8];
  #pragma unroll
  for (int j = 0; j < 8; ++j){
    int k = k0 + j;
    float v = 0.f;
    if (k < DE){
      float y = ws[O_Y + m*DE + k];
      v = fmaxf(y*ws[O_S2 + k] + ws[O_S2 + DE + k], 0.f);
    }
    o8[j] = f2bf(v);
  }
  *(bf16x8*)((unsigned short*)(ws + O_ABF) + (size_t)s*8) = *(bf16x8*)o8;
}

// ---------- E -> bf16 B-frags ----------
__global__ void k_ebf(const float* __restrict__ E, float* __restrict__ ws){
  int s = blockIdx.x*256 + threadIdx.x;   // 2802688 slots (10948 blocks exact)
  int lane = s & 63;
  int ks = (s >> 6) % NKS;
  int ntile = (s >> 6) / NKS;
  int n = ntile*16 + (lane & 15);
  int k0 = ks*32 + (lane >> 4)*8;
  unsigned short o8[8];
  if (n < NENT && k0 + 8 <= DE){
    const float* ep = E + (size_t)n*DE + k0;
    float4 f0 = *(const float4*)ep;
    float4 f1 = *(const float4*)(ep + 4);
    o8[0]=f2bf(f0.x); o8[1]=f2bf(f0.y); o8[2]=f2bf(f0.z); o8[3]=f2bf(f0.w);
    o8[4]=f2bf(f1.x); o8[5]=f2bf(f1.y); o8[6]=f2bf(f1.z); o8[7]=f2bf(f1.w);
  } else {
    #pragma unroll
    for (int j = 0; j < 8; ++j){
      int k = k0 + j;
      o8[j] = f2bf((n < NENT && k < DE) ? E[(size_t)n*DE + k] : 0.f);
    }
  }
  *(bf16x8*)((unsigned short*)(ws + O_EBF) + (size_t)s*8) = *(bf16x8*)o8;
}

// ---------- scores GEMM: bf16 MFMA, n-fastest XCD swizzle for write locality ----------
__global__ __launch_bounds__(256) void k_scores(const float* __restrict__ bias,
                                                const float* __restrict__ ws,
                                                float* __restrict__ out){
  const unsigned short* Abf = (const unsigned short*)(ws + O_ABF);
  const unsigned short* Ebf = (const unsigned short*)(ws + O_EBF);
  int gid = blockIdx.x;                    // 6256 = 16 m-tiles * 391 n-tiles
  int swz = (gid & 7)*782 + (gid >> 3);    // bijective (6256 = 8*782)
  int m_t = swz / 391, n_t = swz % 391;    // n fastest within XCD: streaming writes
  int m0 = m_t*64;
  int lane = threadIdx.x & 63, wid = threadIdx.x >> 6;
  int n0 = n_t*256 + wid*64;
  int lr = lane & 15, lg = lane >> 4;
  const unsigned short* aB = Abf + (size_t)(m_t*4)*NKS*512 + lane*8;
  const unsigned short* bB = Ebf + (size_t)(n0 >> 4)*NKS*512 + lane*8;

  f32x4 acc[4][4] = {};
  bf16x8 aC[4], bC[4], aN[4], bN[4];
  #pragma unroll
  for (int mf = 0; mf < 4; ++mf) aC[mf] = *(const bf16x8*)(aB + (size_t)mf*NKS*512);
  #pragma unroll
  for (int nf = 0; nf < 4; ++nf) bC[nf] = *(const bf16x8*)(bB + (size_t)nf*NKS*512);

  #pragma unroll
  for (int ks = 0; ks < NKS; ++ks){
    if (ks < NKS-1){
      #pragma unroll
      for (int mf = 0; mf < 4; ++mf)
        aN[mf] = *(const bf16x8*)(aB + (size_t)mf*NKS*512 + (ks+1)*512);
      #pragma unroll
      for (int nf = 0; nf < 4; ++nf)
        bN[nf] = *(const bf16x8*)(bB + (size_t)nf*NKS*512 + (ks+1)*512);
    }
    #pragma unroll
    for (int mf = 0; mf < 4; ++mf)
      #pragma unroll
      for (int nf = 0; nf < 4; ++nf)
        acc[mf][nf] = __builtin_amdgcn_mfma_f32_16x16x32_bf16(aC[mf], bC[nf], acc[mf][nf], 0, 0, 0);
    #pragma unroll
    for (int mf = 0; mf < 4; ++mf) aC[mf] = aN[mf];
    #pragma unroll
    for (int nf = 0; nf < 4; ++nf) bC[nf] = bN[nf];
  }

  #pragma unroll
  for (int nf = 0; nf < 4; ++nf){
    int col = n0 + nf*16 + lr;
    if (col < NENT){
      float bv = bias[col];
      #pragma unroll
      for (int mf = 0; mf < 4; ++mf){
        int row = m0 + mf*16 + lg*4;
        #pragma unroll
        for (int r = 0; r < 4; ++r)
          out[(size_t)(row + r)*NENT + col] = sigm(acc[mf][nf][r] + bv);
      }
    }
  }
}

extern "C" void kernel_launch(void* const* d_in, const int* in_sizes, int n_in,
                              void* d_out, int out_size, void* d_ws, size_t ws_size,
                              hipStream_t stream){
  (void)in_sizes; (void)n_in; (void)out_size; (void)ws_size;
  const float* e1    = (const float*)d_in[0];
  const float* r     = (const float*)d_in[1];
  const float* fc1_w = (const float*)d_in[2];
  const float* fc1_b = (const float*)d_in[3];
  const float* fc_w  = (const float*)d_in[4];
  const float* fc_b  = (const float*)d_in[5];
  const float* E     = (const float*)d_in[6];
  const float* bE    = (const float*)d_in[7];
  const float* g0    = (const float*)d_in[8];
  const float* b0    = (const float*)d_in[9];
  const float* g1    = (const float*)d_in[10];
  const float* b1    = (const float*)d_in[11];
  const float* g2    = (const float*)d_in[12];
  const float* b2    = (const float*)d_in[13];
  float* ws  = (float*)d_ws;
  float* out = (float*)d_out;

  k_bn0_part  <<<64,  256, 0, stream>>>(e1, ws);
  k_bn0_final <<<1,   64,  0, stream>>>(g0, b0, ws);
  k_rbf       <<<112, 256, 0, stream>>>(r, ws);
  k_w1bf      <<<32,  256, 0, stream>>>(fc1_w, ws);
  k_fc1m      <<<dim3(16,18), 64, 0, stream>>>(fc1_b, ws);
  k_conv      <<<1024,256, 0, stream>>>(e1, ws);
  k_bn1_final <<<32,  256, 0, stream>>>(g1, b1, ws);
  k_fcwp      <<<768, 256, 0, stream>>>(fc_w, ws);
  k_cvec      <<<200, 256, 0, stream>>>(fc_w, fc_b, ws);
  k_ygemm_m   <<<dim3(16,16), 256, 0, stream>>>(ws);
  k_yreduce   <<<800, 256, 0, stream>>>(ws);
  k_bn2       <<<200, 256, 0, stream>>>(g2, b2, ws);
  k_abf       <<<112, 256, 0, stream>>>(ws);
  k_ebf       <<<10948,256, 0, stream>>>(E, ws);
  k_scores    <<<6256,256, 0, stream>>>(bE, ws, out);
}

// Round 7
// 231.480 us; speedup vs baseline: 6.1171x; 1.2774x over previous
//
#include <hip/hip_runtime.h>
#include <math.h>

#define B_    1024
#define DE    200
#define DR    200
#define NFC   32
#define LFC   9
#define LL    192          // DE - LFC + 1
#define FC1LEN 288         // NFC*LFC
#define FCLEN 6144         // NFC*LL
#define NENT  100000
#define EPSI  1e-5f
#define KPAD  224          // 7*32 for 16x16x32 MFMA
#define NKS   7            // KPAD/32
#define YKS   192          // FCLEN/32
#define YSEG  16           // K-split for y-GEMM

// ---- workspace layout (float offsets). frag region of S slots = S*4 floats ----
#define O_S0    0
#define O_P0    64
#define O_S1    256        // s1[32], t1[32]
#define O_S2    320        // s2[200], t2[200]
#define O_P1    768        // bn1 partials 1024*32*2 -> ends 66304
#define O_RBF   66304      // r A-frags: 28672 slots = 114688 fl -> 180992
#define O_W1BF  180992     // fc1_w B-frags: 8064 slots = 32256 fl -> 213248
#define O_K     213248     // k fp32 1024x288 -> 508160
#define O_CFRAG 508160     // conv bf16 A-frags: 64*192*64 slots = 3145728 fl -> 3653888
#define O_FCWP  3653888    // fcw' B-frags: 16*192*64 slots = 786432 fl -> 4440320
#define O_CVEC  4440320    // c[200] -> 4440576
#define O_PART  4440576    // ygemm partials 16*1024*200 = 3276800 fl -> 7717376
#define O_Y     7717376    // y 1024x200 -> 7922176
#define O_ABF   7922176    // A bf16 frags: 28672 slots = 114688 fl -> 8036864 (32.1 MB)

typedef __attribute__((ext_vector_type(8))) short bf16x8;
typedef __attribute__((ext_vector_type(4))) float f32x4;

__device__ __forceinline__ float sigm(float x){
  return __fdividef(1.0f, 1.0f + __expf(-x));
}

__device__ __forceinline__ unsigned short f2bf(float f){
  unsigned int u = __float_as_uint(f);
  u = (u + 0x7FFFu + ((u >> 16) & 1u)) >> 16;   // RNE
  return (unsigned short)u;
}

__device__ __forceinline__ bf16x8 pack8(float4 f0, float4 f1){
  bf16x8 o;
  o[0]=(short)f2bf(f0.x); o[1]=(short)f2bf(f0.y); o[2]=(short)f2bf(f0.z); o[3]=(short)f2bf(f0.w);
  o[4]=(short)f2bf(f1.x); o[5]=(short)f2bf(f1.y); o[6]=(short)f2bf(f1.z); o[7]=(short)f2bf(f1.w);
  return o;
}

// ---------- BN0 ----------
__global__ void k_bn0_part(const float* __restrict__ e1, float* __restrict__ ws){
  __shared__ float ss[256], sq[256];
  int tid = threadIdx.x;
  float a = 0.f, b = 0.f;
  for (int i = blockIdx.x*256 + tid; i < B_*DE; i += 64*256){
    float v = e1[i]; a += v; b += v*v;
  }
  ss[tid]=a; sq[tid]=b; __syncthreads();
  for (int s=128; s>0; s>>=1){
    if (tid < s){ ss[tid]+=ss[tid+s]; sq[tid]+=sq[tid+s]; }
    __syncthreads();
  }
  if (tid==0){ ws[O_P0+2*blockIdx.x]=ss[0]; ws[O_P0+2*blockIdx.x+1]=sq[0]; }
}

__global__ void k_bn0_final(const float* __restrict__ g, const float* __restrict__ bt,
                            float* __restrict__ ws){
  int tid = threadIdx.x;
  float a = ws[O_P0+2*tid], b = ws[O_P0+2*tid+1];
  for (int o=32; o>0; o>>=1){ a += __shfl_down(a,o); b += __shfl_down(b,o); }
  if (tid==0){
    float n = (float)(B_*DE);
    float m = a/n, v = b/n - m*m;
    float s = rsqrtf(v + EPSI) * g[0];
    ws[O_S0]   = s;
    ws[O_S0+1] = bt[0] - m*s;
  }
}

// ---------- pack r into A-frag layout ----------
__global__ void k_rbf(const float* __restrict__ r, float* __restrict__ ws){
  int s = blockIdx.x*256 + threadIdx.x;   // 28672 slots exact
  int lane = s & 63;
  int ks = (s >> 6) % NKS;
  int mtile = (s >> 6) / NKS;
  int m = mtile*16 + (lane & 15);
  int k0 = ks*32 + (lane >> 4)*8;
  unsigned short o8[8];
  #pragma unroll
  for (int j = 0; j < 8; ++j){
    int k = k0 + j;
    o8[j] = f2bf((k < DR) ? r[m*DR + k] : 0.f);
  }
  *(bf16x8*)((unsigned short*)(ws + O_RBF) + (size_t)s*8) = *(bf16x8*)o8;
}

// ---------- pack fc1_w into B-frag layout ----------
__global__ void k_w1bf(const float* __restrict__ w, float* __restrict__ ws){
  int s = blockIdx.x*256 + threadIdx.x;   // 8064 slots (32 blocks, guarded)
  if (s >= 18*NKS*64) return;
  int lane = s & 63;
  int ks = (s >> 6) % NKS;
  int ntile = (s >> 6) / NKS;
  int n = ntile*16 + (lane & 15);         // < 288
  int k0 = ks*32 + (lane >> 4)*8;
  unsigned short o8[8];
  #pragma unroll
  for (int j = 0; j < 8; ++j){
    int k = k0 + j;
    o8[j] = f2bf((k < DR) ? w[(size_t)n*DR + k] : 0.f);
  }
  *(bf16x8*)((unsigned short*)(ws + O_W1BF) + (size_t)s*8) = *(bf16x8*)o8;
}

// ---------- FC1 via MFMA ----------
__global__ void k_fc1m(const float* __restrict__ bias, float* __restrict__ ws){
  const unsigned short* Rb = (const unsigned short*)(ws + O_RBF);
  const unsigned short* Wb = (const unsigned short*)(ws + O_W1BF);
  int mt = blockIdx.x;        // 0..15
  int nt = blockIdx.y;        // 0..17
  int lane = threadIdx.x;
  int lr = lane & 15, lg = lane >> 4;
  f32x4 acc[4] = {};
  #pragma unroll
  for (int ks = 0; ks < NKS; ++ks){
    bf16x8 b = *(const bf16x8*)(Wb + ((size_t)(nt*NKS + ks)*64 + lane)*8);
    #pragma unroll
    for (int mf = 0; mf < 4; ++mf){
      bf16x8 a = *(const bf16x8*)(Rb + ((size_t)((mt*4+mf)*NKS + ks)*64 + lane)*8);
      acc[mf] = __builtin_amdgcn_mfma_f32_16x16x32_bf16(a, b, acc[mf], 0, 0, 0);
    }
  }
  int col = nt*16 + lr;
  float bv = bias[col];
  #pragma unroll
  for (int mf = 0; mf < 4; ++mf){
    int row = mt*64 + mf*16 + lg*4;
    #pragma unroll
    for (int r = 0; r < 4; ++r)
      ws[O_K + (size_t)(row + r)*FC1LEN + col] = acc[mf][r] + bv;
  }
}

// ---------- conv (BN0 on the fly) -> bf16 A-frag layout + bn1 partials ----------
__global__ void k_conv(const float* __restrict__ e1, float* __restrict__ ws){
  __shared__ float xs[DE];
  __shared__ float kf[FC1LEN];
  int b = blockIdx.x, tid = threadIdx.x;
  float s0v = ws[O_S0], t0v = ws[O_S0+1];
  for (int d = tid; d < DE;     d += 256) xs[d] = e1[b*DE + d]*s0v + t0v;
  for (int i = tid; i < FC1LEN; i += 256) kf[i] = ws[O_K + (size_t)b*FC1LEN + i];
  __syncthreads();
  unsigned short* Cf = (unsigned short*)(ws + O_CFRAG);
  int f = tid >> 3, sub = tid & 7;
  int mtile = b >> 4, mlan = b & 15;
  float kr[LFC];
  #pragma unroll
  for (int j = 0; j < LFC; ++j) kr[j] = kf[f*LFC + j];
  float sum = 0.f, sq = 0.f;
  #pragma unroll
  for (int g = 0; g < 3; ++g){
    unsigned short o8[8];
    int l0 = sub*24 + g*8;
    #pragma unroll
    for (int t = 0; t < 8; ++t){
      int l = l0 + t;
      float acc = 0.f;
      #pragma unroll
      for (int j = 0; j < LFC; ++j) acc += xs[l+j]*kr[j];
      o8[t] = f2bf(acc);
      sum += acc; sq += acc*acc;
    }
    int k0 = f*LL + l0;
    int ks = k0 >> 5;
    int lane_w = ((k0 >> 3) & 3)*16 + mlan;
    size_t slot = (size_t)(mtile*YKS + ks)*64 + lane_w;
    *(bf16x8*)(Cf + slot*8) = *(bf16x8*)o8;
  }
  for (int o = 1; o < 8; o <<= 1){ sum += __shfl_xor(sum,o); sq += __shfl_xor(sq,o); }
  if (sub == 0){
    ws[O_P1 + (b*NFC + f)*2    ] = sum;
    ws[O_P1 + (b*NFC + f)*2 + 1] = sq;
  }
}

__global__ void k_bn1_final(const float* __restrict__ g, const float* __restrict__ bt,
                            float* __restrict__ ws){
  __shared__ float ss[256], sq[256];
  int f = blockIdx.x, tid = threadIdx.x;
  float a = 0.f, b = 0.f;
  for (int i = tid; i < B_; i += 256){
    a += ws[O_P1 + (i*NFC + f)*2];
    b += ws[O_P1 + (i*NFC + f)*2 + 1];
  }
  ss[tid]=a; sq[tid]=b; __syncthreads();
  for (int s=128; s>0; s>>=1){
    if (tid < s){ ss[tid]+=ss[tid+s]; sq[tid]+=sq[tid+s]; }
    __syncthreads();
  }
  if (tid==0){
    float n = (float)(B_*LL);
    float m = ss[0]/n, v = sq[0]/n - m*m;
    float s = rsqrtf(v + EPSI) * g[f];
    ws[O_S1 + f]       = s;
    ws[O_S1 + NFC + f] = bt[f] - m*s;
  }
}

// ---------- pack fcw*s1[f] into B-frag layout (16 n-tiles, padded) ----------
__global__ void k_fcwp(const float* __restrict__ fcw, float* __restrict__ ws){
  int s = blockIdx.x*256 + threadIdx.x;   // 196608 slots (768 blocks)
  int lane = s & 63;
  int ks = (s >> 6) % YKS;
  int ntile = (s >> 6) / YKS;
  int n = ntile*16 + (lane & 15);         // < 256
  int k0 = ks*32 + (lane >> 4)*8;         // < 6144
  int f = (k0 >> 6) / 3;                  // k0/192
  float sc = ws[O_S1 + f];
  unsigned short o8[8];
  if (n < DE){
    const float* p = fcw + (size_t)n*FCLEN + k0;
    float4 f0 = *(const float4*)p;
    float4 f1 = *(const float4*)(p + 4);
    o8[0]=f2bf(f0.x*sc); o8[1]=f2bf(f0.y*sc); o8[2]=f2bf(f0.z*sc); o8[3]=f2bf(f0.w*sc);
    o8[4]=f2bf(f1.x*sc); o8[5]=f2bf(f1.y*sc); o8[6]=f2bf(f1.z*sc); o8[7]=f2bf(f1.w*sc);
  } else {
    #pragma unroll
    for (int j = 0; j < 8; ++j) o8[j] = 0;
  }
  *(bf16x8*)((unsigned short*)(ws + O_FCWP) + (size_t)s*8) = *(bf16x8*)o8;
}

// ---------- c[o] = sum_i t1[f(i)]*fcw[o,i] + fc_b[o] ----------
__global__ void k_cvec(const float* __restrict__ fcw, const float* __restrict__ fcb,
                       float* __restrict__ ws){
  __shared__ float t1s[NFC];
  __shared__ float red[256];
  int o = blockIdx.x, tid = threadIdx.x;
  if (tid < NFC) t1s[tid] = ws[O_S1 + NFC + tid];
  __syncthreads();
  float acc = 0.f;
  for (int i = tid; i < FCLEN; i += 256)
    acc += fcw[(size_t)o*FCLEN + i] * t1s[i/LL];
  red[tid] = acc; __syncthreads();
  for (int s=128; s>0; s>>=1){
    if (tid < s) red[tid] += red[tid+s];
    __syncthreads();
  }
  if (tid==0) ws[O_CVEC + o] = red[0] + fcb[o];
}

// ---------- y-GEMM via MFMA, both sides frag-coalesced, 16-way K-split ----------
__global__ __launch_bounds__(256) void k_ygemm_m(float* __restrict__ ws){
  const unsigned short* Cb = (const unsigned short*)(ws + O_CFRAG);
  const unsigned short* Wb = (const unsigned short*)(ws + O_FCWP);
  int mt = blockIdx.x;      // 0..15
  int seg = blockIdx.y;     // 0..15
  int tid = threadIdx.x;
  int lane = tid & 63, wid = tid >> 6;
  int lr = lane & 15, lg = lane >> 4;
  f32x4 acc[4][4] = {};     // [mf][nf], nt = wid*4+nf
  #pragma unroll 4
  for (int ksl = 0; ksl < 12; ++ksl){
    int ks = seg*12 + ksl;
    bf16x8 a[4], bfr[4];
    #pragma unroll
    for (int mf = 0; mf < 4; ++mf)
      a[mf] = *(const bf16x8*)(Cb + ((size_t)((mt*4+mf)*YKS + ks)*64 + lane)*8);
    #pragma unroll
    for (int nf = 0; nf < 4; ++nf){
      int nt = wid*4 + nf;
      bfr[nf] = *(const bf16x8*)(Wb + ((size_t)(nt*YKS + ks)*64 + lane)*8);
    }
    #pragma unroll
    for (int mf = 0; mf < 4; ++mf)
      #pragma unroll
      for (int nf = 0; nf < 4; ++nf)
        acc[mf][nf] = __builtin_amdgcn_mfma_f32_16x16x32_bf16(a[mf], bfr[nf], acc[mf][nf], 0, 0, 0);
  }
  float* part = ws + O_PART + (size_t)seg*(B_*DE);
  #pragma unroll
  for (int nf = 0; nf < 4; ++nf){
    int col = (wid*4 + nf)*16 + lr;
    if (col < DE){
      #pragma unroll
      for (int mf = 0; mf < 4; ++mf){
        int row = mt*64 + mf*16 + lg*4;
        #pragma unroll
        for (int r = 0; r < 4; ++r)
          part[(size_t)(row + r)*DE + col] = acc[mf][nf][r];
      }
    }
  }
}

__global__ void k_yreduce(float* __restrict__ ws){
  int i = blockIdx.x*256 + threadIdx.x;   // 204800
  int o = i % DE;
  float y = ws[O_CVEC + o];
  #pragma unroll
  for (int s = 0; s < YSEG; ++s) y += ws[O_PART + (size_t)s*(B_*DE) + i];
  ws[O_Y + i] = y;
}

// ---------- BN2 stats ----------
__global__ void k_bn2(const float* __restrict__ g, const float* __restrict__ bt,
                      float* __restrict__ ws){
  __shared__ float ss[256], sq[256];
  int o = blockIdx.x, tid = threadIdx.x;
  float a = 0.f, b = 0.f;
  for (int i = tid; i < B_; i += 256){
    float v = ws[O_Y + i*DE + o];
    a += v; b += v*v;
  }
  ss[tid]=a; sq[tid]=b; __syncthreads();
  for (int s=128; s>0; s>>=1){
    if (tid < s){ ss[tid]+=ss[tid+s]; sq[tid]+=sq[tid+s]; }
    __syncthreads();
  }
  if (tid==0){
    float n = (float)B_;
    float m = ss[0]/n, v = sq[0]/n - m*m;
    float s = rsqrtf(v + EPSI) * g[o];
    ws[O_S2 + o]      = s;
    ws[O_S2 + DE + o] = bt[o] - m*s;
  }
}

// ---------- BN2-apply + ReLU + bf16 A-frags ----------
__global__ void k_abf(float* __restrict__ ws){
  int s = blockIdx.x*256 + threadIdx.x;   // 28672 slots exact
  int lane = s & 63;
  int ks = (s >> 6) % NKS;
  int mtile = (s >> 6) / NKS;
  int m = mtile*16 + (lane & 15);
  int k0 = ks*32 + (lane >> 4)*8;
  unsigned short o8[8];
  #pragma unroll
  for (int j = 0; j < 8; ++j){
    int k = k0 + j;
    float v = 0.f;
    if (k < DE){
      float y = ws[O_Y + m*DE + k];
      v = fmaxf(y*ws[O_S2 + k] + ws[O_S2 + DE + k], 0.f);
    }
    o8[j] = f2bf(v);
  }
  *(bf16x8*)((unsigned short*)(ws + O_ABF) + (size_t)s*8) = *(bf16x8*)o8;
}

// ---------- scores GEMM: E-resident-in-register, m-loop, nt stores ----------
// grid 782 = 2 m-halves x 391 n-stripes (256 cols). Block: 256 thr = 4 waves.
// Wave: 64 cols x 512 rows. E slice (64 cols x 224 K) held in 112 VGPRs as
// bf16 B-frags, converted from fp32 once. Inner loop: 4 A-frag loads (L2-hot)
// + 16 MFMA per K-step. Write-bound by design.
__global__ __launch_bounds__(256, 2) void k_scores(const float* __restrict__ E,
                                                   const float* __restrict__ bias,
                                                   const float* __restrict__ ws,
                                                   float* __restrict__ out){
  const unsigned short* Abf = (const unsigned short*)(ws + O_ABF);
  int orig = blockIdx.x;            // 782 = 8*97 + 6
  int xcd = orig & 7, pos = orig >> 3;
  int wgid = (xcd < 6) ? xcd*98 + pos : 588 + (xcd - 6)*97 + pos;  // bijective
  int mh = wgid / 391, ns = wgid - mh*391;   // n fastest within XCD
  int tid = threadIdx.x;
  int lane = tid & 63, wid = tid >> 6;
  int lr = lane & 15, lg = lane >> 4;

  // ---- E resident: 4 n-tiles x 7 ks, fp32 -> bf16 once ----
  bf16x8 ebf[4][7];
  int   colv[4];
  float bv[4];
  #pragma unroll
  for (int nf = 0; nf < 4; ++nf){
    int col = (ns*16 + wid*4 + nf)*16 + lr;
    colv[nf] = col;
    int nc = (col < NENT) ? col : (NENT-1);
    bv[nf] = bias[nc];
    const float* ep = E + (size_t)nc*DE;
    #pragma unroll
    for (int ks = 0; ks < NKS; ++ks){
      int k0 = ks*32 + lg*8;
      if (k0 + 8 <= DE){
        float4 f0 = *(const float4*)(ep + k0);
        float4 f1 = *(const float4*)(ep + k0 + 4);
        ebf[nf][ks] = pack8(f0, f1);
      } else {
        ebf[nf][ks] = (bf16x8){0,0,0,0,0,0,0,0};
      }
    }
  }

  const unsigned short* aBase = Abf + (size_t)(mh*8)*1792*8 + lane*8;
  #pragma unroll 1
  for (int t = 0; t < 8; ++t){
    const unsigned short* ap = aBase + (size_t)t*1792*8;
    bf16x8 aC[4], aN[4];
    #pragma unroll
    for (int mf = 0; mf < 4; ++mf) aC[mf] = *(const bf16x8*)(ap + (size_t)(mf*NKS)*512);
    f32x4 acc[4][4] = {};
    #pragma unroll
    for (int ks = 0; ks < NKS; ++ks){
      if (ks < NKS-1){
        #pragma unroll
        for (int mf = 0; mf < 4; ++mf)
          aN[mf] = *(const bf16x8*)(ap + (size_t)(mf*NKS + ks + 1)*512);
      }
      #pragma unroll
      for (int mf = 0; mf < 4; ++mf)
        #pragma unroll
        for (int nf = 0; nf < 4; ++nf)
          acc[mf][nf] = __builtin_amdgcn_mfma_f32_16x16x32_bf16(aC[mf], ebf[nf][ks], acc[mf][nf], 0, 0, 0);
      #pragma unroll
      for (int mf = 0; mf < 4; ++mf) aC[mf] = aN[mf];
    }
    int row0 = (mh*8 + t)*64 + lg*4;
    #pragma unroll
    for (int nf = 0; nf < 4; ++nf){
      if (colv[nf] < NENT){
        #pragma unroll
        for (int mf = 0; mf < 4; ++mf){
          size_t base = (size_t)(row0 + mf*16)*NENT + colv[nf];
          #pragma unroll
          for (int r = 0; r < 4; ++r)
            __builtin_nontemporal_store(sigm(acc[mf][nf][r] + bv[nf]), &out[base + (size_t)r*NENT]);
        }
      }
    }
  }
}

extern "C" void kernel_launch(void* const* d_in, const int* in_sizes, int n_in,
                              void* d_out, int out_size, void* d_ws, size_t ws_size,
                              hipStream_t stream){
  (void)in_sizes; (void)n_in; (void)out_size; (void)ws_size;
  const float* e1    = (const float*)d_in[0];
  const float* r     = (const float*)d_in[1];
  const float* fc1_w = (const float*)d_in[2];
  const float* fc1_b = (const float*)d_in[3];
  const float* fc_w  = (const float*)d_in[4];
  const float* fc_b  = (const float*)d_in[5];
  const float* E     = (const float*)d_in[6];
  const float* bE    = (const float*)d_in[7];
  const float* g0    = (const float*)d_in[8];
  const float* b0    = (const float*)d_in[9];
  const float* g1    = (const float*)d_in[10];
  const float* b1    = (const float*)d_in[11];
  const float* g2    = (const float*)d_in[12];
  const float* b2    = (const float*)d_in[13];
  float* ws  = (float*)d_ws;
  float* out = (float*)d_out;

  k_bn0_part  <<<64,  256, 0, stream>>>(e1, ws);
  k_bn0_final <<<1,   64,  0, stream>>>(g0, b0, ws);
  k_rbf       <<<112, 256, 0, stream>>>(r, ws);
  k_w1bf      <<<32,  256, 0, stream>>>(fc1_w, ws);
  k_fc1m      <<<dim3(16,18), 64, 0, stream>>>(fc1_b, ws);
  k_conv      <<<1024,256, 0, stream>>>(e1, ws);
  k_bn1_final <<<32,  256, 0, stream>>>(g1, b1, ws);
  k_fcwp      <<<768, 256, 0, stream>>>(fc_w, ws);
  k_cvec      <<<200, 256, 0, stream>>>(fc_w, fc_b, ws);
  k_ygemm_m   <<<dim3(16,16), 256, 0, stream>>>(ws);
  k_yreduce   <<<800, 256, 0, stream>>>(ws);
  k_bn2       <<<200, 256, 0, stream>>>(g2, b2, ws);
  k_abf       <<<112, 256, 0, stream>>>(ws);
  k_scores    <<<782, 256, 0, stream>>>(E, bE, ws, out);
}

// Round 9
// 200.865 us; speedup vs baseline: 7.0495x; 1.1524x over previous
//
#include <hip/hip_runtime.h>
#include <math.h>

#define B_    1024
#define DE    200
#define DR    200
#define NFC   32
#define LFC   9
#define LL    192          // DE - LFC + 1
#define FC1LEN 288         // NFC*LFC
#define FCLEN 6144         // NFC*LL
#define NENT  100000
#define EPSI  1e-5f
#define KPAD  224          // 7*32 for 16x16x32 MFMA
#define NKS   7            // KPAD/32
#define YKS   192          // FCLEN/32
#define YSEG  16           // K-split for y-GEMM

// ---- workspace layout (float offsets). frag region of S slots = S*4 floats ----
#define O_S0    0
#define O_P0    64
#define O_S1    256        // s1[32], t1[32]
#define O_S2    320        // s2[200], t2[200]
#define O_P1    768        // bn1 partials 1024*32*2 -> ends 66304
#define O_RBF   66304      // r A-frags: 28672 slots = 114688 fl -> 180992
#define O_W1BF  180992     // fc1_w B-frags: 8064 slots = 32256 fl -> 213248
#define O_K     213248     // k fp32 1024x288 -> 508160
#define O_CFRAG 508160     // conv bf16 A-frags: 64*192*64 slots = 3145728 fl -> 3653888
#define O_FCWP  3653888    // fcw' B-frags: 16*192*64 slots = 786432 fl -> 4440320
#define O_CVEC  4440320    // c[200] -> 4440576
#define O_PART  4440576    // ygemm partials 16*1024*200 = 3276800 fl -> 7717376
#define O_Y     7717376    // y 1024x200 -> 7922176
#define O_ABF   7922176    // A bf16 frags: 28672 slots = 114688 fl -> 8036864 (32.1 MB)

typedef __attribute__((ext_vector_type(8))) short bf16x8;
typedef __attribute__((ext_vector_type(4))) float f32x4;

__device__ __forceinline__ float sigm(float x){
  return __fdividef(1.0f, 1.0f + __expf(-x));
}

__device__ __forceinline__ unsigned short f2bf(float f){
  unsigned int u = __float_as_uint(f);
  u = (u + 0x7FFFu + ((u >> 16) & 1u)) >> 16;   // RNE
  return (unsigned short)u;
}

__device__ __forceinline__ bf16x8 pack8(float4 f0, float4 f1){
  bf16x8 o;
  o[0]=(short)f2bf(f0.x); o[1]=(short)f2bf(f0.y); o[2]=(short)f2bf(f0.z); o[3]=(short)f2bf(f0.w);
  o[4]=(short)f2bf(f1.x); o[5]=(short)f2bf(f1.y); o[6]=(short)f2bf(f1.z); o[7]=(short)f2bf(f1.w);
  return o;
}

// ---------- BN0 ----------
__global__ void k_bn0_part(const float* __restrict__ e1, float* __restrict__ ws){
  __shared__ float ss[256], sq[256];
  int tid = threadIdx.x;
  float a = 0.f, b = 0.f;
  for (int i = blockIdx.x*256 + tid; i < B_*DE; i += 64*256){
    float v = e1[i]; a += v; b += v*v;
  }
  ss[tid]=a; sq[tid]=b; __syncthreads();
  for (int s=128; s>0; s>>=1){
    if (tid < s){ ss[tid]+=ss[tid+s]; sq[tid]+=sq[tid+s]; }
    __syncthreads();
  }
  if (tid==0){ ws[O_P0+2*blockIdx.x]=ss[0]; ws[O_P0+2*blockIdx.x+1]=sq[0]; }
}

__global__ void k_bn0_final(const float* __restrict__ g, const float* __restrict__ bt,
                            float* __restrict__ ws){
  int tid = threadIdx.x;
  float a = ws[O_P0+2*tid], b = ws[O_P0+2*tid+1];
  for (int o=32; o>0; o>>=1){ a += __shfl_down(a,o); b += __shfl_down(b,o); }
  if (tid==0){
    float n = (float)(B_*DE);
    float m = a/n, v = b/n - m*m;
    float s = rsqrtf(v + EPSI) * g[0];
    ws[O_S0]   = s;
    ws[O_S0+1] = bt[0] - m*s;
  }
}

// ---------- pack r (A-frags) + fc1_w (B-frags), fused ----------
__global__ void k_pack(const float* __restrict__ r, const float* __restrict__ w,
                       float* __restrict__ ws){
  int blk = blockIdx.x;
  if (blk < 112){
    int s = blk*256 + threadIdx.x;        // 28672 slots exact
    int lane = s & 63;
    int ks = (s >> 6) % NKS;
    int mtile = (s >> 6) / NKS;
    int m = mtile*16 + (lane & 15);
    int k0 = ks*32 + (lane >> 4)*8;
    unsigned short o8[8];
    #pragma unroll
    for (int j = 0; j < 8; ++j){
      int k = k0 + j;
      o8[j] = f2bf((k < DR) ? r[m*DR + k] : 0.f);
    }
    *(bf16x8*)((unsigned short*)(ws + O_RBF) + (size_t)s*8) = *(bf16x8*)o8;
  } else {
    int s = (blk-112)*256 + threadIdx.x;  // 8064 slots (guarded)
    if (s >= 18*NKS*64) return;
    int lane = s & 63;
    int ks = (s >> 6) % NKS;
    int ntile = (s >> 6) / NKS;
    int n = ntile*16 + (lane & 15);       // < 288
    int k0 = ks*32 + (lane >> 4)*8;
    unsigned short o8[8];
    #pragma unroll
    for (int j = 0; j < 8; ++j){
      int k = k0 + j;
      o8[j] = f2bf((k < DR) ? w[(size_t)n*DR + k] : 0.f);
    }
    *(bf16x8*)((unsigned short*)(ws + O_W1BF) + (size_t)s*8) = *(bf16x8*)o8;
  }
}

// ---------- FC1 via MFMA ----------
__global__ void k_fc1m(const float* __restrict__ bias, float* __restrict__ ws){
  const unsigned short* Rb = (const unsigned short*)(ws + O_RBF);
  const unsigned short* Wb = (const unsigned short*)(ws + O_W1BF);
  int mt = blockIdx.x;        // 0..15
  int nt = blockIdx.y;        // 0..17
  int lane = threadIdx.x;
  int lr = lane & 15, lg = lane >> 4;
  f32x4 acc[4] = {};
  #pragma unroll
  for (int ks = 0; ks < NKS; ++ks){
    bf16x8 b = *(const bf16x8*)(Wb + ((size_t)(nt*NKS + ks)*64 + lane)*8);
    #pragma unroll
    for (int mf = 0; mf < 4; ++mf){
      bf16x8 a = *(const bf16x8*)(Rb + ((size_t)((mt*4+mf)*NKS + ks)*64 + lane)*8);
      acc[mf] = __builtin_amdgcn_mfma_f32_16x16x32_bf16(a, b, acc[mf], 0, 0, 0);
    }
  }
  int col = nt*16 + lr;
  float bv = bias[col];
  #pragma unroll
  for (int mf = 0; mf < 4; ++mf){
    int row = mt*64 + mf*16 + lg*4;
    #pragma unroll
    for (int r = 0; r < 4; ++r)
      ws[O_K + (size_t)(row + r)*FC1LEN + col] = acc[mf][r] + bv;
  }
}

// ---------- conv (BN0 on the fly) -> bf16 A-frag layout + bn1 partials ----------
__global__ void k_conv(const float* __restrict__ e1, float* __restrict__ ws){
  __shared__ float xs[DE];
  __shared__ float kf[FC1LEN];
  int b = blockIdx.x, tid = threadIdx.x;
  float s0v = ws[O_S0], t0v = ws[O_S0+1];
  for (int d = tid; d < DE;     d += 256) xs[d] = e1[b*DE + d]*s0v + t0v;
  for (int i = tid; i < FC1LEN; i += 256) kf[i] = ws[O_K + (size_t)b*FC1LEN + i];
  __syncthreads();
  unsigned short* Cf = (unsigned short*)(ws + O_CFRAG);
  int f = tid >> 3, sub = tid & 7;
  int mtile = b >> 4, mlan = b & 15;
  float kr[LFC];
  #pragma unroll
  for (int j = 0; j < LFC; ++j) kr[j] = kf[f*LFC + j];
  float sum = 0.f, sq = 0.f;
  #pragma unroll
  for (int g = 0; g < 3; ++g){
    unsigned short o8[8];
    int l0 = sub*24 + g*8;
    #pragma unroll
    for (int t = 0; t < 8; ++t){
      int l = l0 + t;
      float acc = 0.f;
      #pragma unroll
      for (int j = 0; j < LFC; ++j) acc += xs[l+j]*kr[j];
      o8[t] = f2bf(acc);
      sum += acc; sq += acc*acc;
    }
    int k0 = f*LL + l0;
    int ks = k0 >> 5;
    int lane_w = ((k0 >> 3) & 3)*16 + mlan;
    size_t slot = (size_t)(mtile*YKS + ks)*64 + lane_w;
    *(bf16x8*)(Cf + slot*8) = *(bf16x8*)o8;
  }
  for (int o = 1; o < 8; o <<= 1){ sum += __shfl_xor(sum,o); sq += __shfl_xor(sq,o); }
  if (sub == 0){
    ws[O_P1 + (b*NFC + f)*2    ] = sum;
    ws[O_P1 + (b*NFC + f)*2 + 1] = sq;
  }
}

__global__ void k_bn1_final(const float* __restrict__ g, const float* __restrict__ bt,
                            float* __restrict__ ws){
  __shared__ float ss[256], sq[256];
  int f = blockIdx.x, tid = threadIdx.x;
  float a = 0.f, b = 0.f;
  for (int i = tid; i < B_; i += 256){
    a += ws[O_P1 + (i*NFC + f)*2];
    b += ws[O_P1 + (i*NFC + f)*2 + 1];
  }
  ss[tid]=a; sq[tid]=b; __syncthreads();
  for (int s=128; s>0; s>>=1){
    if (tid < s){ ss[tid]+=ss[tid+s]; sq[tid]+=sq[tid+s]; }
    __syncthreads();
  }
  if (tid==0){
    float n = (float)(B_*LL);
    float m = ss[0]/n, v = sq[0]/n - m*m;
    float s = rsqrtf(v + EPSI) * g[f];
    ws[O_S1 + f]       = s;
    ws[O_S1 + NFC + f] = bt[f] - m*s;
  }
}

// ---------- pack fcw*s1[f] into B-frag layout (16 n-tiles, padded) ----------
__global__ void k_fcwp(const float* __restrict__ fcw, float* __restrict__ ws){
  int s = blockIdx.x*256 + threadIdx.x;   // 196608 slots (768 blocks)
  int lane = s & 63;
  int ks = (s >> 6) % YKS;
  int ntile = (s >> 6) / YKS;
  int n = ntile*16 + (lane & 15);         // < 256
  int k0 = ks*32 + (lane >> 4)*8;         // < 6144
  int f = (k0 >> 6) / 3;                  // k0/192
  float sc = ws[O_S1 + f];
  unsigned short o8[8];
  if (n < DE){
    const float* p = fcw + (size_t)n*FCLEN + k0;
    float4 f0 = *(const float4*)p;
    float4 f1 = *(const float4*)(p + 4);
    o8[0]=f2bf(f0.x*sc); o8[1]=f2bf(f0.y*sc); o8[2]=f2bf(f0.z*sc); o8[3]=f2bf(f0.w*sc);
    o8[4]=f2bf(f1.x*sc); o8[5]=f2bf(f1.y*sc); o8[6]=f2bf(f1.z*sc); o8[7]=f2bf(f1.w*sc);
  } else {
    #pragma unroll
    for (int j = 0; j < 8; ++j) o8[j] = 0;
  }
  *(bf16x8*)((unsigned short*)(ws + O_FCWP) + (size_t)s*8) = *(bf16x8*)o8;
}

// ---------- c[o] = sum_i t1[f(i)]*fcw[o,i] + fc_b[o] ----------
__global__ void k_cvec(const float* __restrict__ fcw, const float* __restrict__ fcb,
                       float* __restrict__ ws){
  __shared__ float t1s[NFC];
  __shared__ float red[256];
  int o = blockIdx.x, tid = threadIdx.x;
  if (tid < NFC) t1s[tid] = ws[O_S1 + NFC + tid];
  __syncthreads();
  float acc = 0.f;
  for (int i = tid; i < FCLEN; i += 256)
    acc += fcw[(size_t)o*FCLEN + i] * t1s[i/LL];
  red[tid] = acc; __syncthreads();
  for (int s=128; s>0; s>>=1){
    if (tid < s) red[tid] += red[tid+s];
    __syncthreads();
  }
  if (tid==0) ws[O_CVEC + o] = red[0] + fcb[o];
}

// ---------- y-GEMM via MFMA, both sides frag-coalesced, 16-way K-split ----------
__global__ __launch_bounds__(256) void k_ygemm_m(float* __restrict__ ws){
  const unsigned short* Cb = (const unsigned short*)(ws + O_CFRAG);
  const unsigned short* Wb = (const unsigned short*)(ws + O_FCWP);
  int mt = blockIdx.x;      // 0..15
  int seg = blockIdx.y;     // 0..15
  int tid = threadIdx.x;
  int lane = tid & 63, wid = tid >> 6;
  int lr = lane & 15, lg = lane >> 4;
  f32x4 acc[4][4] = {};     // [mf][nf], nt = wid*4+nf
  #pragma unroll 4
  for (int ksl = 0; ksl < 12; ++ksl){
    int ks = seg*12 + ksl;
    bf16x8 a[4], bfr[4];
    #pragma unroll
    for (int mf = 0; mf < 4; ++mf)
      a[mf] = *(const bf16x8*)(Cb + ((size_t)((mt*4+mf)*YKS + ks)*64 + lane)*8);
    #pragma unroll
    for (int nf = 0; nf < 4; ++nf){
      int nt = wid*4 + nf;
      bfr[nf] = *(const bf16x8*)(Wb + ((size_t)(nt*YKS + ks)*64 + lane)*8);
    }
    #pragma unroll
    for (int mf = 0; mf < 4; ++mf)
      #pragma unroll
      for (int nf = 0; nf < 4; ++nf)
        acc[mf][nf] = __builtin_amdgcn_mfma_f32_16x16x32_bf16(a[mf], bfr[nf], acc[mf][nf], 0, 0, 0);
  }
  float* part = ws + O_PART + (size_t)seg*(B_*DE);
  #pragma unroll
  for (int nf = 0; nf < 4; ++nf){
    int col = (wid*4 + nf)*16 + lr;
    if (col < DE){
      #pragma unroll
      for (int mf = 0; mf < 4; ++mf){
        int row = mt*64 + mf*16 + lg*4;
        #pragma unroll
        for (int r = 0; r < 4; ++r)
          part[(size_t)(row + r)*DE + col] = acc[mf][nf][r];
      }
    }
  }
}

__global__ void k_yreduce(float* __restrict__ ws){
  int i = blockIdx.x*256 + threadIdx.x;   // 204800
  int o = i % DE;
  float y = ws[O_CVEC + o];
  #pragma unroll
  for (int s = 0; s < YSEG; ++s) y += ws[O_PART + (size_t)s*(B_*DE) + i];
  ws[O_Y + i] = y;
}

// ---------- BN2 stats ----------
__global__ void k_bn2(const float* __restrict__ g, const float* __restrict__ bt,
                      float* __restrict__ ws){
  __shared__ float ss[256], sq[256];
  int o = blockIdx.x, tid = threadIdx.x;
  float a = 0.f, b = 0.f;
  for (int i = tid; i < B_; i += 256){
    float v = ws[O_Y + i*DE + o];
    a += v; b += v*v;
  }
  ss[tid]=a; sq[tid]=b; __syncthreads();
  for (int s=128; s>0; s>>=1){
    if (tid < s){ ss[tid]+=ss[tid+s]; sq[tid]+=sq[tid+s]; }
    __syncthreads();
  }
  if (tid==0){
    float n = (float)B_;
    float m = ss[0]/n, v = sq[0]/n - m*m;
    float s = rsqrtf(v + EPSI) * g[o];
    ws[O_S2 + o]      = s;
    ws[O_S2 + DE + o] = bt[o] - m*s;
  }
}

// ---------- BN2-apply + ReLU + bf16 A-frags ----------
__global__ void k_abf(float* __restrict__ ws){
  int s = blockIdx.x*256 + threadIdx.x;   // 28672 slots exact
  int lane = s & 63;
  int ks = (s >> 6) % NKS;
  int mtile = (s >> 6) / NKS;
  int m = mtile*16 + (lane & 15);
  int k0 = ks*32 + (lane >> 4)*8;
  unsigned short o8[8];
  #pragma unroll
  for (int j = 0; j < 8; ++j){
    int k = k0 + j;
    float v = 0.f;
    if (k < DE){
      float y = ws[O_Y + m*DE + k];
      v = fmaxf(y*ws[O_S2 + k] + ws[O_S2 + DE + k], 0.f);
    }
    o8[j] = f2bf(v);
  }
  *(bf16x8*)((unsigned short*)(ws + O_ABF) + (size_t)s*8) = *(bf16x8*)o8;
}

// ---------- scores GEMM: E-resident regs, LDS-transpose epilogue, 1KB row stores ----------
// grid 782 (identity order: consecutive blocks = adjacent col stripes, same rows).
// Block: 4 waves; 512 rows x 256 cols. Epilogue: acc -> LDS (64x256 f32) ->
// each wave nt-stores full 1KB row-chunks (16 cache lines, same DRAM page).
__global__ __launch_bounds__(256, 2) void k_scores(const float* __restrict__ E,
                                                   const float* __restrict__ bias,
                                                   const float* __restrict__ ws,
                                                   float* __restrict__ out){
  __shared__ float tile[64*256];          // 64 KB
  const unsigned short* Abf = (const unsigned short*)(ws + O_ABF);
  int wgid = blockIdx.x;                  // identity: ns-fastest chip-wide
  int mh = wgid / 391, ns = wgid - mh*391;
  int tid = threadIdx.x;
  int lane = tid & 63, wid = tid >> 6;
  int lr = lane & 15, lg = lane >> 4;

  // ---- E resident: 4 n-tiles x 7 ks, fp32 -> bf16 once ----
  bf16x8 ebf[4][7];
  float bv[4];
  #pragma unroll
  for (int nf = 0; nf < 4; ++nf){
    int col = ns*256 + wid*64 + nf*16 + lr;
    int nc = (col < NENT) ? col : (NENT-1);
    bv[nf] = bias[nc];
    const float* ep = E + (size_t)nc*DE;
    #pragma unroll
    for (int ks = 0; ks < NKS; ++ks){
      int k0 = ks*32 + lg*8;
      if (k0 + 8 <= DE){
        float4 f0 = *(const float4*)(ep + k0);
        float4 f1 = *(const float4*)(ep + k0 + 4);
        ebf[nf][ks] = pack8(f0, f1);
      } else {
        ebf[nf][ks] = (bf16x8){0,0,0,0,0,0,0,0};
      }
    }
  }

  const unsigned short* aBase = Abf + (size_t)(mh*8)*1792*8 + lane*8;
  int col0 = ns*256;
  #pragma unroll 1
  for (int t = 0; t < 8; ++t){
    const unsigned short* ap = aBase + (size_t)t*1792*8;
    bf16x8 aC[4], aN[4];
    #pragma unroll
    for (int mf = 0; mf < 4; ++mf) aC[mf] = *(const bf16x8*)(ap + (size_t)(mf*NKS)*512);
    f32x4 acc[4][4] = {};
    #pragma unroll
    for (int ks = 0; ks < NKS; ++ks){
      if (ks < NKS-1){
        #pragma unroll
        for (int mf = 0; mf < 4; ++mf)
          aN[mf] = *(const bf16x8*)(ap + (size_t)(mf*NKS + ks + 1)*512);
      }
      #pragma unroll
      for (int mf = 0; mf < 4; ++mf)
        #pragma unroll
        for (int nf = 0; nf < 4; ++nf)
          acc[mf][nf] = __builtin_amdgcn_mfma_f32_16x16x32_bf16(aC[mf], ebf[nf][ks], acc[mf][nf], 0, 0, 0);
      #pragma unroll
      for (int mf = 0; mf < 4; ++mf) aC[mf] = aN[mf];
    }
    // ---- epilogue: sigmoid -> LDS [64 rows][256 cols] ----
    __syncthreads();                       // previous iteration's reads done
    #pragma unroll
    for (int mf = 0; mf < 4; ++mf)
      #pragma unroll
      for (int nf = 0; nf < 4; ++nf){
        int lrow = mf*16 + lg*4;
        int lcol = wid*64 + nf*16 + lr;
        #pragma unroll
        for (int r = 0; r < 4; ++r)
          tile[(lrow + r)*256 + lcol] = sigm(acc[mf][nf][r] + bv[nf]);
      }
    __syncthreads();
    // ---- wave-wide 1KB contiguous nt stores ----
    int row0 = (mh*8 + t)*64;
    #pragma unroll
    for (int p = 0; p < 16; ++p){
      int lrow = p*4 + wid;
      int lcol = lane*4;
      f32x4 v = *(const f32x4*)&tile[lrow*256 + lcol];
      int gc = col0 + lcol;
      if (gc < NENT)
        __builtin_nontemporal_store(v, (f32x4*)&out[(size_t)(row0 + lrow)*NENT + gc]);
    }
  }
}

extern "C" void kernel_launch(void* const* d_in, const int* in_sizes, int n_in,
                              void* d_out, int out_size, void* d_ws, size_t ws_size,
                              hipStream_t stream){
  (void)in_sizes; (void)n_in; (void)out_size; (void)ws_size;
  const float* e1    = (const float*)d_in[0];
  const float* r     = (const float*)d_in[1];
  const float* fc1_w = (const float*)d_in[2];
  const float* fc1_b = (const float*)d_in[3];
  const float* fc_w  = (const float*)d_in[4];
  const float* fc_b  = (const float*)d_in[5];
  const float* E     = (const float*)d_in[6];
  const float* bE    = (const float*)d_in[7];
  const float* g0    = (const float*)d_in[8];
  const float* b0    = (const float*)d_in[9];
  const float* g1    = (const float*)d_in[10];
  const float* b1    = (const float*)d_in[11];
  const float* g2    = (const float*)d_in[12];
  const float* b2    = (const float*)d_in[13];
  float* ws  = (float*)d_ws;
  float* out = (float*)d_out;

  k_bn0_part  <<<64,  256, 0, stream>>>(e1, ws);
  k_bn0_final <<<1,   64,  0, stream>>>(g0, b0, ws);
  k_pack      <<<144, 256, 0, stream>>>(r, fc1_w, ws);
  k_fc1m      <<<dim3(16,18), 64, 0, stream>>>(fc1_b, ws);
  k_conv      <<<1024,256, 0, stream>>>(e1, ws);
  k_bn1_final <<<32,  256, 0, stream>>>(g1, b1, ws);
  k_fcwp      <<<768, 256, 0, stream>>>(fc_w, ws);
  k_cvec      <<<200, 256, 0, stream>>>(fc_w, fc_b, ws);
  k_ygemm_m   <<<dim3(16,16), 256, 0, stream>>>(ws);
  k_yreduce   <<<800, 256, 0, stream>>>(ws);
  k_bn2       <<<200, 256, 0, stream>>>(g2, b2, ws);
  k_abf       <<<112, 256, 0, stream>>>(ws);
  k_scores    <<<782, 256, 0, stream>>>(E, bE, ws, out);
}

// Round 10
// 197.692 us; speedup vs baseline: 7.1626x; 1.0161x over previous
//
#include <hip/hip_runtime.h>
#include <math.h>

#define B_    1024
#define DE    200
#define DR    200
#define NFC   32
#define LFC   9
#define LL    192          // DE - LFC + 1
#define FC1LEN 288         // NFC*LFC
#define FCLEN 6144         // NFC*LL
#define NENT  100000
#define EPSI  1e-5f
#define KPAD  224          // 7*32 for 16x16x32 MFMA
#define NKS   7            // KPAD/32
#define YKS   192          // FCLEN/32
#define YSEG  16           // K-split for y-GEMM

// ---- workspace layout (float offsets). frag region of S slots = S*4 floats ----
#define O_S0    0
#define O_P0    64
#define O_S1    256        // s1[32], t1[32]
#define O_S2    320        // s2[200], t2[200]
#define O_P1    768        // bn1 partials 1024*32*2 -> ends 66304
#define O_RBF   66304      // r A-frags: 28672 slots = 114688 fl -> 180992
#define O_W1BF  180992     // fc1_w B-frags: 8064 slots = 32256 fl -> 213248
#define O_K     213248     // k fp32 1024x288 -> 508160
#define O_CFRAG 508160     // conv bf16 A-frags: 64*192*64 slots = 3145728 fl -> 3653888
#define O_FCWP  3653888    // fcw' B-frags: 16*192*64 slots = 786432 fl -> 4440320
#define O_CVEC  4440320    // c[200] -> 4440576
#define O_PART  4440576    // ygemm partials 16*1024*200 = 3276800 fl -> 7717376
#define O_Y     7717376    // y 1024x200 -> 7922176
#define O_ABF   7922176    // A bf16 frags: 28672 slots = 114688 fl -> 8036864 (32.1 MB)

typedef __attribute__((ext_vector_type(8))) short bf16x8;
typedef __attribute__((ext_vector_type(4))) float f32x4;

__device__ __forceinline__ float sigm(float x){
  return __fdividef(1.0f, 1.0f + __expf(-x));
}

__device__ __forceinline__ unsigned short f2bf(float f){
  unsigned int u = __float_as_uint(f);
  u = (u + 0x7FFFu + ((u >> 16) & 1u)) >> 16;   // RNE
  return (unsigned short)u;
}

__device__ __forceinline__ bf16x8 pack8v(f32x4 f0, f32x4 f1){
  bf16x8 o;
  o[0]=(short)f2bf(f0[0]); o[1]=(short)f2bf(f0[1]); o[2]=(short)f2bf(f0[2]); o[3]=(short)f2bf(f0[3]);
  o[4]=(short)f2bf(f1[0]); o[5]=(short)f2bf(f1[1]); o[6]=(short)f2bf(f1[2]); o[7]=(short)f2bf(f1[3]);
  return o;
}

// ---------- pack r (A-frags) + fc1_w (B-frags) + BN0 partials, fused ----------
__global__ void k_pack0(const float* __restrict__ r, const float* __restrict__ w,
                        const float* __restrict__ e1, float* __restrict__ ws){
  __shared__ float ss[256], sq[256];
  int blk = blockIdx.x;
  if (blk < 112){
    int s = blk*256 + threadIdx.x;        // 28672 slots exact
    int lane = s & 63;
    int ks = (s >> 6) % NKS;
    int mtile = (s >> 6) / NKS;
    int m = mtile*16 + (lane & 15);
    int k0 = ks*32 + (lane >> 4)*8;
    unsigned short o8[8];
    #pragma unroll
    for (int j = 0; j < 8; ++j){
      int k = k0 + j;
      o8[j] = f2bf((k < DR) ? r[m*DR + k] : 0.f);
    }
    *(bf16x8*)((unsigned short*)(ws + O_RBF) + (size_t)s*8) = *(bf16x8*)o8;
  } else if (blk < 144){
    int s = (blk-112)*256 + threadIdx.x;  // 8064 slots (guarded)
    if (s >= 18*NKS*64) return;
    int lane = s & 63;
    int ks = (s >> 6) % NKS;
    int ntile = (s >> 6) / NKS;
    int n = ntile*16 + (lane & 15);       // < 288
    int k0 = ks*32 + (lane >> 4)*8;
    unsigned short o8[8];
    #pragma unroll
    for (int j = 0; j < 8; ++j){
      int k = k0 + j;
      o8[j] = f2bf((k < DR) ? w[(size_t)n*DR + k] : 0.f);
    }
    *(bf16x8*)((unsigned short*)(ws + O_W1BF) + (size_t)s*8) = *(bf16x8*)o8;
  } else {
    // BN0 partials (64 blocks)
    int bb = blk - 144, tid = threadIdx.x;
    float a = 0.f, b = 0.f;
    for (int i = bb*256 + tid; i < B_*DE; i += 64*256){
      float v = e1[i]; a += v; b += v*v;
    }
    ss[tid]=a; sq[tid]=b; __syncthreads();
    for (int s=128; s>0; s>>=1){
      if (tid < s){ ss[tid]+=ss[tid+s]; sq[tid]+=sq[tid+s]; }
      __syncthreads();
    }
    if (tid==0){ ws[O_P0+2*bb]=ss[0]; ws[O_P0+2*bb+1]=sq[0]; }
  }
}

__global__ void k_bn0_final(const float* __restrict__ g, const float* __restrict__ bt,
                            float* __restrict__ ws){
  int tid = threadIdx.x;
  float a = ws[O_P0+2*tid], b = ws[O_P0+2*tid+1];
  for (int o=32; o>0; o>>=1){ a += __shfl_down(a,o); b += __shfl_down(b,o); }
  if (tid==0){
    float n = (float)(B_*DE);
    float m = a/n, v = b/n - m*m;
    float s = rsqrtf(v + EPSI) * g[0];
    ws[O_S0]   = s;
    ws[O_S0+1] = bt[0] - m*s;
  }
}

// ---------- FC1 via MFMA ----------
__global__ void k_fc1m(const float* __restrict__ bias, float* __restrict__ ws){
  const unsigned short* Rb = (const unsigned short*)(ws + O_RBF);
  const unsigned short* Wb = (const unsigned short*)(ws + O_W1BF);
  int mt = blockIdx.x;        // 0..15
  int nt = blockIdx.y;        // 0..17
  int lane = threadIdx.x;
  int lr = lane & 15, lg = lane >> 4;
  f32x4 acc[4] = {};
  #pragma unroll
  for (int ks = 0; ks < NKS; ++ks){
    bf16x8 b = *(const bf16x8*)(Wb + ((size_t)(nt*NKS + ks)*64 + lane)*8);
    #pragma unroll
    for (int mf = 0; mf < 4; ++mf){
      bf16x8 a = *(const bf16x8*)(Rb + ((size_t)((mt*4+mf)*NKS + ks)*64 + lane)*8);
      acc[mf] = __builtin_amdgcn_mfma_f32_16x16x32_bf16(a, b, acc[mf], 0, 0, 0);
    }
  }
  int col = nt*16 + lr;
  float bv = bias[col];
  #pragma unroll
  for (int mf = 0; mf < 4; ++mf){
    int row = mt*64 + mf*16 + lg*4;
    #pragma unroll
    for (int r = 0; r < 4; ++r)
      ws[O_K + (size_t)(row + r)*FC1LEN + col] = acc[mf][r] + bv;
  }
}

// ---------- conv (BN0 on the fly) -> bf16 A-frag layout + bn1 partials ----------
__global__ void k_conv(const float* __restrict__ e1, float* __restrict__ ws){
  __shared__ float xs[DE];
  __shared__ float kf[FC1LEN];
  int b = blockIdx.x, tid = threadIdx.x;
  float s0v = ws[O_S0], t0v = ws[O_S0+1];
  for (int d = tid; d < DE;     d += 256) xs[d] = e1[b*DE + d]*s0v + t0v;
  for (int i = tid; i < FC1LEN; i += 256) kf[i] = ws[O_K + (size_t)b*FC1LEN + i];
  __syncthreads();
  unsigned short* Cf = (unsigned short*)(ws + O_CFRAG);
  int f = tid >> 3, sub = tid & 7;
  int mtile = b >> 4, mlan = b & 15;
  float kr[LFC];
  #pragma unroll
  for (int j = 0; j < LFC; ++j) kr[j] = kf[f*LFC + j];
  float sum = 0.f, sq = 0.f;
  #pragma unroll
  for (int g = 0; g < 3; ++g){
    unsigned short o8[8];
    int l0 = sub*24 + g*8;
    #pragma unroll
    for (int t = 0; t < 8; ++t){
      int l = l0 + t;
      float acc = 0.f;
      #pragma unroll
      for (int j = 0; j < LFC; ++j) acc += xs[l+j]*kr[j];
      o8[t] = f2bf(acc);
      sum += acc; sq += acc*acc;
    }
    int k0 = f*LL + l0;
    int ks = k0 >> 5;
    int lane_w = ((k0 >> 3) & 3)*16 + mlan;
    size_t slot = (size_t)(mtile*YKS + ks)*64 + lane_w;
    *(bf16x8*)(Cf + slot*8) = *(bf16x8*)o8;
  }
  for (int o = 1; o < 8; o <<= 1){ sum += __shfl_xor(sum,o); sq += __shfl_xor(sq,o); }
  if (sub == 0){
    ws[O_P1 + (b*NFC + f)*2    ] = sum;
    ws[O_P1 + (b*NFC + f)*2 + 1] = sq;
  }
}

__global__ void k_bn1_final(const float* __restrict__ g, const float* __restrict__ bt,
                            float* __restrict__ ws){
  __shared__ float ss[256], sq[256];
  int f = blockIdx.x, tid = threadIdx.x;
  float a = 0.f, b = 0.f;
  for (int i = tid; i < B_; i += 256){
    a += ws[O_P1 + (i*NFC + f)*2];
    b += ws[O_P1 + (i*NFC + f)*2 + 1];
  }
  ss[tid]=a; sq[tid]=b; __syncthreads();
  for (int s=128; s>0; s>>=1){
    if (tid < s){ ss[tid]+=ss[tid+s]; sq[tid]+=sq[tid+s]; }
    __syncthreads();
  }
  if (tid==0){
    float n = (float)(B_*LL);
    float m = ss[0]/n, v = sq[0]/n - m*m;
    float s = rsqrtf(v + EPSI) * g[f];
    ws[O_S1 + f]       = s;
    ws[O_S1 + NFC + f] = bt[f] - m*s;
  }
}

// ---------- pack fcw*s1[f] into B-frag layout + cvec, fused ----------
__global__ void k_fcwp_cvec(const float* __restrict__ fcw, const float* __restrict__ fcb,
                            float* __restrict__ ws){
  __shared__ float shm[256];
  int blk = blockIdx.x;
  if (blk < 768){
    int s = blk*256 + threadIdx.x;   // 196608 slots
    int lane = s & 63;
    int ks = (s >> 6) % YKS;
    int ntile = (s >> 6) / YKS;
    int n = ntile*16 + (lane & 15);         // < 256
    int k0 = ks*32 + (lane >> 4)*8;         // < 6144
    int f = (k0 >> 6) / 3;                  // k0/192
    float sc = ws[O_S1 + f];
    unsigned short o8[8];
    if (n < DE){
      const float* p = fcw + (size_t)n*FCLEN + k0;
      float4 f0 = *(const float4*)p;
      float4 f1 = *(const float4*)(p + 4);
      o8[0]=f2bf(f0.x*sc); o8[1]=f2bf(f0.y*sc); o8[2]=f2bf(f0.z*sc); o8[3]=f2bf(f0.w*sc);
      o8[4]=f2bf(f1.x*sc); o8[5]=f2bf(f1.y*sc); o8[6]=f2bf(f1.z*sc); o8[7]=f2bf(f1.w*sc);
    } else {
      #pragma unroll
      for (int j = 0; j < 8; ++j) o8[j] = 0;
    }
    *(bf16x8*)((unsigned short*)(ws + O_FCWP) + (size_t)s*8) = *(bf16x8*)o8;
  } else {
    // cvec: c[o] = sum_i t1[f(i)]*fcw[o,i] + fc_b[o]
    __shared__ float t1s[NFC];
    int o = blk - 768, tid = threadIdx.x;
    if (tid < NFC) t1s[tid] = ws[O_S1 + NFC + tid];
    __syncthreads();
    float acc = 0.f;
    for (int i = tid; i < FCLEN; i += 256)
      acc += fcw[(size_t)o*FCLEN + i] * t1s[i/LL];
    shm[tid] = acc; __syncthreads();
    for (int s=128; s>0; s>>=1){
      if (tid < s) shm[tid] += shm[tid+s];
      __syncthreads();
    }
    if (tid==0) ws[O_CVEC + o] = shm[0] + fcb[o];
  }
}

// ---------- y-GEMM via MFMA, both sides frag-coalesced, 16-way K-split ----------
__global__ __launch_bounds__(256) void k_ygemm_m(float* __restrict__ ws){
  const unsigned short* Cb = (const unsigned short*)(ws + O_CFRAG);
  const unsigned short* Wb = (const unsigned short*)(ws + O_FCWP);
  int mt = blockIdx.x;      // 0..15
  int seg = blockIdx.y;     // 0..15
  int tid = threadIdx.x;
  int lane = tid & 63, wid = tid >> 6;
  int lr = lane & 15, lg = lane >> 4;
  f32x4 acc[4][4] = {};     // [mf][nf], nt = wid*4+nf
  #pragma unroll 4
  for (int ksl = 0; ksl < 12; ++ksl){
    int ks = seg*12 + ksl;
    bf16x8 a[4], bfr[4];
    #pragma unroll
    for (int mf = 0; mf < 4; ++mf)
      a[mf] = *(const bf16x8*)(Cb + ((size_t)((mt*4+mf)*YKS + ks)*64 + lane)*8);
    #pragma unroll
    for (int nf = 0; nf < 4; ++nf){
      int nt = wid*4 + nf;
      bfr[nf] = *(const bf16x8*)(Wb + ((size_t)(nt*YKS + ks)*64 + lane)*8);
    }
    #pragma unroll
    for (int mf = 0; mf < 4; ++mf)
      #pragma unroll
      for (int nf = 0; nf < 4; ++nf)
        acc[mf][nf] = __builtin_amdgcn_mfma_f32_16x16x32_bf16(a[mf], bfr[nf], acc[mf][nf], 0, 0, 0);
  }
  float* part = ws + O_PART + (size_t)seg*(B_*DE);
  #pragma unroll
  for (int nf = 0; nf < 4; ++nf){
    int col = (wid*4 + nf)*16 + lr;
    if (col < DE){
      #pragma unroll
      for (int mf = 0; mf < 4; ++mf){
        int row = mt*64 + mf*16 + lg*4;
        #pragma unroll
        for (int r = 0; r < 4; ++r)
          part[(size_t)(row + r)*DE + col] = acc[mf][nf][r];
      }
    }
  }
}

__global__ void k_yreduce(float* __restrict__ ws){
  int i = blockIdx.x*256 + threadIdx.x;   // 204800
  int o = i % DE;
  float y = ws[O_CVEC + o];
  #pragma unroll
  for (int s = 0; s < YSEG; ++s) y += ws[O_PART + (size_t)s*(B_*DE) + i];
  ws[O_Y + i] = y;
}

// ---------- BN2 stats ----------
__global__ void k_bn2(const float* __restrict__ g, const float* __restrict__ bt,
                      float* __restrict__ ws){
  __shared__ float ss[256], sq[256];
  int o = blockIdx.x, tid = threadIdx.x;
  float a = 0.f, b = 0.f;
  for (int i = tid; i < B_; i += 256){
    float v = ws[O_Y + i*DE + o];
    a += v; b += v*v;
  }
  ss[tid]=a; sq[tid]=b; __syncthreads();
  for (int s=128; s>0; s>>=1){
    if (tid < s){ ss[tid]+=ss[tid+s]; sq[tid]+=sq[tid+s]; }
    __syncthreads();
  }
  if (tid==0){
    float n = (float)B_;
    float m = ss[0]/n, v = sq[0]/n - m*m;
    float s = rsqrtf(v + EPSI) * g[o];
    ws[O_S2 + o]      = s;
    ws[O_S2 + DE + o] = bt[o] - m*s;
  }
}

// ---------- BN2-apply + ReLU + bf16 A-frags ----------
__global__ void k_abf(float* __restrict__ ws){
  int s = blockIdx.x*256 + threadIdx.x;   // 28672 slots exact
  int lane = s & 63;
  int ks = (s >> 6) % NKS;
  int mtile = (s >> 6) / NKS;
  int m = mtile*16 + (lane & 15);
  int k0 = ks*32 + (lane >> 4)*8;
  unsigned short o8[8];
  #pragma unroll
  for (int j = 0; j < 8; ++j){
    int k = k0 + j;
    float v = 0.f;
    if (k < DE){
      float y = ws[O_Y + m*DE + k];
      v = fmaxf(y*ws[O_S2 + k] + ws[O_S2 + DE + k], 0.f);
    }
    o8[j] = f2bf(v);
  }
  *(bf16x8*)((unsigned short*)(ws + O_ABF) + (size_t)s*8) = *(bf16x8*)o8;
}

// ---------- scores GEMM: one block per 256-col stripe, all 1024 rows ----------
// grid 391. E slice read ONCE per block (nt loads, 205KB), bf16 in regs.
// 16 t-tiles: 28 A-frag loads (L2-hot) + 112 MFMA + LDS transpose + 1KB nt stores.
__global__ __launch_bounds__(256, 2) void k_scores(const float* __restrict__ E,
                                                   const float* __restrict__ bias,
                                                   const float* __restrict__ ws,
                                                   float* __restrict__ out){
  __shared__ float tile[64*256];          // 64 KB
  const unsigned short* Abf = (const unsigned short*)(ws + O_ABF);
  int ns = blockIdx.x;                    // 0..390
  int tid = threadIdx.x;
  int lane = tid & 63, wid = tid >> 6;
  int lr = lane & 15, lg = lane >> 4;

  // ---- E resident: 4 n-tiles x 7 ks, fp32 -> bf16 once (nontemporal reads) ----
  bf16x8 ebf[4][7];
  float bv[4];
  #pragma unroll
  for (int nf = 0; nf < 4; ++nf){
    int col = ns*256 + wid*64 + nf*16 + lr;
    int nc = (col < NENT) ? col : (NENT-1);
    bv[nf] = bias[nc];
    const float* ep = E + (size_t)nc*DE;
    #pragma unroll
    for (int ks = 0; ks < NKS; ++ks){
      int k0 = ks*32 + lg*8;
      if (k0 + 8 <= DE){
        f32x4 f0 = __builtin_nontemporal_load((const f32x4*)(ep + k0));
        f32x4 f1 = __builtin_nontemporal_load((const f32x4*)(ep + k0 + 4));
        ebf[nf][ks] = pack8v(f0, f1);
      } else {
        ebf[nf][ks] = (bf16x8){0,0,0,0,0,0,0,0};
      }
    }
  }

  const unsigned short* aBase = Abf + lane*8;
  int col0 = ns*256;
  #pragma unroll 1
  for (int t = 0; t < 16; ++t){
    const unsigned short* ap = aBase + (size_t)t*1792*8;
    bf16x8 aC[4], aN[4];
    #pragma unroll
    for (int mf = 0; mf < 4; ++mf) aC[mf] = *(const bf16x8*)(ap + (size_t)(mf*NKS)*512);
    f32x4 acc[4][4] = {};
    #pragma unroll
    for (int ks = 0; ks < NKS; ++ks){
      if (ks < NKS-1){
        #pragma unroll
        for (int mf = 0; mf < 4; ++mf)
          aN[mf] = *(const bf16x8*)(ap + (size_t)(mf*NKS + ks + 1)*512);
      }
      #pragma unroll
      for (int mf = 0; mf < 4; ++mf)
        #pragma unroll
        for (int nf = 0; nf < 4; ++nf)
          acc[mf][nf] = __builtin_amdgcn_mfma_f32_16x16x32_bf16(aC[mf], ebf[nf][ks], acc[mf][nf], 0, 0, 0);
      #pragma unroll
      for (int mf = 0; mf < 4; ++mf) aC[mf] = aN[mf];
    }
    // ---- epilogue: sigmoid -> LDS [64 rows][256 cols] ----
    __syncthreads();                       // previous iteration's reads done
    #pragma unroll
    for (int mf = 0; mf < 4; ++mf)
      #pragma unroll
      for (int nf = 0; nf < 4; ++nf){
        int lrow = mf*16 + lg*4;
        int lcol = wid*64 + nf*16 + lr;
        #pragma unroll
        for (int r = 0; r < 4; ++r)
          tile[(lrow + r)*256 + lcol] = sigm(acc[mf][nf][r] + bv[nf]);
      }
    __syncthreads();
    // ---- wave-wide 1KB contiguous nt stores ----
    int row0 = t*64;
    #pragma unroll
    for (int p = 0; p < 16; ++p){
      int lrow = p*4 + wid;
      int lcol = lane*4;
      f32x4 v = *(const f32x4*)&tile[lrow*256 + lcol];
      int gc = col0 + lcol;
      if (gc < NENT)
        __builtin_nontemporal_store(v, (f32x4*)&out[(size_t)(row0 + lrow)*NENT + gc]);
    }
  }
}

extern "C" void kernel_launch(void* const* d_in, const int* in_sizes, int n_in,
                              void* d_out, int out_size, void* d_ws, size_t ws_size,
                              hipStream_t stream){
  (void)in_sizes; (void)n_in; (void)out_size; (void)ws_size;
  const float* e1    = (const float*)d_in[0];
  const float* r     = (const float*)d_in[1];
  const float* fc1_w = (const float*)d_in[2];
  const float* fc1_b = (const float*)d_in[3];
  const float* fc_w  = (const float*)d_in[4];
  const float* fc_b  = (const float*)d_in[5];
  const float* E     = (const float*)d_in[6];
  const float* bE    = (const float*)d_in[7];
  const float* g0    = (const float*)d_in[8];
  const float* b0    = (const float*)d_in[9];
  const float* g1    = (const float*)d_in[10];
  const float* b1    = (const float*)d_in[11];
  const float* g2    = (const float*)d_in[12];
  const float* b2    = (const float*)d_in[13];
  float* ws  = (float*)d_ws;
  float* out = (float*)d_out;

  k_pack0     <<<208, 256, 0, stream>>>(r, fc1_w, e1, ws);
  k_bn0_final <<<1,   64,  0, stream>>>(g0, b0, ws);
  k_fc1m      <<<dim3(16,18), 64, 0, stream>>>(fc1_b, ws);
  k_conv      <<<1024,256, 0, stream>>>(e1, ws);
  k_bn1_final <<<32,  256, 0, stream>>>(g1, b1, ws);
  k_fcwp_cvec <<<968, 256, 0, stream>>>(fc_w, fc_b, ws);
  k_ygemm_m   <<<dim3(16,16), 256, 0, stream>>>(ws);
  k_yreduce   <<<800, 256, 0, stream>>>(ws);
  k_bn2       <<<200, 256, 0, stream>>>(g2, b2, ws);
  k_abf       <<<112, 256, 0, stream>>>(ws);
  k_scores    <<<391, 256, 0, stream>>>(E, bE, ws, out);
}